// Round 12
// baseline (135.738 us; speedup 1.0000x reference)
//
#include <hip/hip_runtime.h>
#include <hip/hip_bf16.h>
#include <math.h>

#define B_ 2
#define H_ 16
#define N_ 8192
#define D_ 64
#define R_ 7
#define BLOCK_ 256
#define SAMPLE_ 256
#define BH_ (B_*H_)
#define NBLK_ (N_/BLOCK_)

#define CHUNK_ 128           // keys staged per chunk
#define PADK 72              // Ks row stride: 144 B
#define PADV 132             // Vt row stride: 264 B

typedef __attribute__((ext_vector_type(8))) short bf16x8;
typedef __attribute__((ext_vector_type(4))) short bf16x4;
typedef __attribute__((ext_vector_type(4))) float f32x4;
typedef __attribute__((ext_vector_type(2))) unsigned int u32x2;
typedef __attribute__((ext_vector_type(4))) unsigned int u32x4;

__device__ inline unsigned short f2bf(float x) {
  __hip_bfloat16 h = __float2bfloat16(x);
  return *(unsigned short*)&h;
}
__device__ inline unsigned int pack2bf(float a, float b) {
  return (unsigned int)f2bf(a) | ((unsigned int)f2bf(b) << 16);
}
__device__ inline float fexp2(float x) {
#if __has_builtin(__builtin_amdgcn_exp2f)
  return __builtin_amdgcn_exp2f(x);
#else
  return exp2f(x);
#endif
}

// PV mfma: D = A(16x16: d x k) * B(16x16: k x q), K=16, bf16
__device__ inline f32x4 mfma16(bf16x4 a, bf16x4 b, f32x4 c) {
#if __has_builtin(__builtin_amdgcn_mfma_f32_16x16x16bf16_1k)
  return __builtin_amdgcn_mfma_f32_16x16x16bf16_1k(a, b, c, 0, 0, 0);
#else
  asm volatile("v_mfma_f32_16x16x16_bf16 %0, %1, %2, %0" : "+v"(c) : "v"(a), "v"(b));
  return c;
#endif
}

// ---------------- Kernel 1: LSH hash (R10 — b128 broadcast spdT) ----------------
__global__ __launch_bounds__(256) void hash_kernel(
    const float* __restrict__ q, const float* __restrict__ k,
    const float* __restrict__ pd, int* __restrict__ qh, int* __restrict__ kh) {
  __shared__ __align__(16) float spdT[R_][D_];   // [r][d]
  for (int i = threadIdx.x; i < D_ * R_; i += blockDim.x) {
    int d = i / R_, r = i - d * R_;              // pd[d*R + r]
    spdT[r][d] = pd[i];
  }
  __syncthreads();
  int tid = blockIdx.x * blockDim.x + threadIdx.x;
  const int half = BH_ * N_;
  const float* src = (tid < half) ? q : k;
  int* dst = (tid < half) ? qh : kh;
  int row = (tid < half) ? tid : tid - half;
  const float4* x4 = (const float4*)(src + (size_t)row * D_);
  float4 x[16];
#pragma unroll
  for (int j = 0; j < 16; j++) x[j] = x4[j];
  int bin = 0;
#pragma unroll
  for (int r = 0; r < R_; r++) {
    float a = 0.f;
#pragma unroll
    for (int j = 0; j < 16; j++) {
      float4 sp = *(const float4*)&spdT[r][4 * j];
      a = fmaf(x[j].x, sp.x, a);
      a = fmaf(x[j].y, sp.y, a);
      a = fmaf(x[j].z, sp.z, a);
      a = fmaf(x[j].w, sp.w, a);
    }
    bin |= (a > 0.f) ? (1 << r) : 0;
  }
  dst[row] = bin ^ (bin >> 1);
}

// ---------------- Kernel 2: stable counting sort, 256 threads/WG (R10) ----------------
__global__ __launch_bounds__(256) void sort_kernel(
    const int* __restrict__ qh, const int* __restrict__ kh,
    int* __restrict__ qidx, int* __restrict__ kidx) {
  int g = blockIdx.x;
  int bh = g & (BH_ - 1);
  bool isK = g >= BH_;
  const int* h = (isK ? kh : qh) + (size_t)bh * N_;
  int* idx = (isK ? kidx : qidx) + (size_t)bh * N_;
  __shared__ unsigned short hist[128][256];   // 64 KiB
  __shared__ int segsum[128][8];
  __shared__ int tot[128];
  __shared__ int off[128];
  const int t = threadIdx.x;

  {  // zero hist (u32x4 = 16 B stores)
    u32x4* hz = (u32x4*)hist;
    for (int i = t; i < 4096; i += 256) hz[i] = (u32x4){0u, 0u, 0u, 0u};
  }
  __syncthreads();

  const int base = t * 32;
  int hv[32];
#pragma unroll
  for (int j = 0; j < 32; j++) hv[j] = h[base + j];
#pragma unroll
  for (int j = 0; j < 32; j++) hist[hv[j]][t]++;
  __syncthreads();

  for (int task = t; task < 1024; task += 256) {
    int b = task >> 3, s = task & 7;
    int sum = 0;
#pragma unroll
    for (int u = 0; u < 32; u++) sum += hist[b][s * 32 + u];
    segsum[b][s] = sum;
  }
  __syncthreads();

  if (t < 128) {
    int run = 0;
#pragma unroll
    for (int s = 0; s < 8; s++) { int x = segsum[t][s]; segsum[t][s] = run; run += x; }
    tot[t] = run;
  }
  __syncthreads();

  if (t == 0) {
    int run = 0;
    for (int b = 0; b < 128; b++) { off[b] = run; run += tot[b]; }
  }
  __syncthreads();

  for (int task = t; task < 1024; task += 256) {
    int b = task >> 3, s = task & 7;
    int run = off[b] + segsum[b][s];
#pragma unroll
    for (int u = 0; u < 32; u++) {
      int x = hist[b][s * 32 + u];
      hist[b][s * 32 + u] = (unsigned short)run;
      run += x;
    }
  }
  __syncthreads();

#pragma unroll
  for (int j = 0; j < 32; j++) {
    int c = hv[j];
    int p = hist[c][t]++;
    idx[p] = base + j;
  }
}

// ---------------- Kernel 3: gather sampled K/V (256-thread blocks) ----------------
__global__ __launch_bounds__(256) void subgather_kernel(
    const float* __restrict__ key, const float* __restrict__ val,
    const int* __restrict__ kidx, const int* __restrict__ samp,
    float* __restrict__ ksub, float* __restrict__ vsub, int* __restrict__ sblk) {
  int sidx = blockIdx.x * 4 + (threadIdx.x >> 6);   // 0 .. BH*SAMPLE-1
  int bh = sidx >> 8;                                // SAMPLE_=256
  int d = threadIdx.x & 63;
  int pos = samp[sidx];
  int row = kidx[(size_t)bh * N_ + pos];
  ksub[(size_t)sidx * D_ + d] = key[((size_t)bh * N_ + row) * D_ + d];
  vsub[(size_t)sidx * D_ + d] = val[((size_t)bh * N_ + row) * D_ + d];
  if (d == 0) sblk[sidx] = pos >> 8;                 // BLOCK_=256
}

// ---------------- Kernel 4: MFMA fused attention, T14 @ 170-reg budget ----------------
// grid = BH*NBLK, 512 threads (8 waves). __launch_bounds__(512,3): occupancy is
// pinned at 3 waves/SIMD anyway (R11 evidence), so claim the 170-reg budget —
// this is what R7's async staging lacked (its (512,4)=128-reg cap caused the
// spill). Issue chunk c+1 global loads BEFORE phase(c); after the barrier only
// cvt+ds_write. Verification gate: WRITE_SIZE must stay ~65.5 MB (no scratch).
__global__ __launch_bounds__(512, 3) void attn_kernel(
    const float* __restrict__ query, const float* __restrict__ key,
    const float* __restrict__ value,
    const int* __restrict__ qidx, const int* __restrict__ kidx,
    const float* __restrict__ ksub, const float* __restrict__ vsub,
    const int* __restrict__ sblk, float* __restrict__ out) {
  __shared__ __align__(16) unsigned short KsL[CHUNK_ * PADK];   // 18432 B
  __shared__ __align__(16) unsigned short VtL[D_ * PADV];       // 16896 B
  __shared__ int sbs[CHUNK_];

  const int bh = blockIdx.x / NBLK_;
  const int blk = blockIdx.x - bh * NBLK_;
  const int tid = threadIdx.x;
  const int w = tid >> 6;       // wave 0..7
  const int lane = tid & 63;
  const int lg = lane >> 4;
  const int lr = lane & 15;
  const float FOLD = 0.18033688011112042f;   // (1/8) * log2(e)
  const int kp = tid >> 3, dq = tid & 7;     // staging: (k-pair, d-octant)

  // ---- staged-register chunk (raw f32; cvt happens in the write segment) ----
  float4 sk0a, sk0b, sk1a, sk1b, sv0a, sv0b, sv1a, sv1b;
  int sreg = 0;

  auto load_block = [&](int c) {
    size_t ib = (size_t)bh * N_ + blk * BLOCK_ + c * CHUNK_ + 2 * kp;
    int r0 = kidx[ib], r1 = kidx[ib + 1];
    const float* k0 = key + ((size_t)bh * N_ + r0) * D_ + dq * 8;
    const float* k1 = key + ((size_t)bh * N_ + r1) * D_ + dq * 8;
    const float* v0 = value + ((size_t)bh * N_ + r0) * D_ + dq * 8;
    const float* v1 = value + ((size_t)bh * N_ + r1) * D_ + dq * 8;
    sk0a = *(const float4*)k0; sk0b = *(const float4*)(k0 + 4);
    sk1a = *(const float4*)k1; sk1b = *(const float4*)(k1 + 4);
    sv0a = *(const float4*)v0; sv0b = *(const float4*)(v0 + 4);
    sv1a = *(const float4*)v1; sv1b = *(const float4*)(v1 + 4);
  };
  auto load_sample = [&](int c) {
    size_t b0 = ((size_t)bh * SAMPLE_ + c * CHUNK_ + 2 * kp) * D_ + dq * 8;
    sk0a = *(const float4*)(ksub + b0);      sk0b = *(const float4*)(ksub + b0 + 4);
    sk1a = *(const float4*)(ksub + b0 + D_); sk1b = *(const float4*)(ksub + b0 + D_ + 4);
    sv0a = *(const float4*)(vsub + b0);      sv0b = *(const float4*)(vsub + b0 + 4);
    sv1a = *(const float4*)(vsub + b0 + D_); sv1b = *(const float4*)(vsub + b0 + D_ + 4);
    if (tid < CHUNK_) sreg = sblk[(size_t)bh * SAMPLE_ + c * CHUNK_ + tid];
  };
  auto write_kv = [&](bool issb) {
    u32x4 pk0 = (u32x4){pack2bf(sk0a.x, sk0a.y), pack2bf(sk0a.z, sk0a.w),
                        pack2bf(sk0b.x, sk0b.y), pack2bf(sk0b.z, sk0b.w)};
    u32x4 pk1 = (u32x4){pack2bf(sk1a.x, sk1a.y), pack2bf(sk1a.z, sk1a.w),
                        pack2bf(sk1b.x, sk1b.y), pack2bf(sk1b.z, sk1b.w)};
    *(u32x4*)&KsL[(2 * kp + 0) * PADK + dq * 8] = pk0;
    *(u32x4*)&KsL[(2 * kp + 1) * PADK + dq * 8] = pk1;
    float a0[8] = {sv0a.x, sv0a.y, sv0a.z, sv0a.w, sv0b.x, sv0b.y, sv0b.z, sv0b.w};
    float a1[8] = {sv1a.x, sv1a.y, sv1a.z, sv1a.w, sv1b.x, sv1b.y, sv1b.z, sv1b.w};
#pragma unroll
    for (int j = 0; j < 8; j++)
      *(unsigned*)&VtL[(dq * 8 + j) * PADV + 2 * kp] = pack2bf(a0[j], a1[j]);
    if (issb && tid < CHUNK_) sbs[tid] = sreg;
  };

  // ---- prologue: issue chunk-0 + own-Q loads, write, barrier ----
  load_block(0);
  int qrw[2];
  qrw[0] = qidx[(size_t)bh * N_ + blk * BLOCK_ + w * 32 + lr];
  qrw[1] = qidx[(size_t)bh * N_ + blk * BLOCK_ + w * 32 + 16 + lr];
  float4 qraw[2][4];
#pragma unroll
  for (int qt = 0; qt < 2; qt++) {
    const float* qp = query + ((size_t)bh * N_ + qrw[qt]) * D_ + lg * 8;
    qraw[qt][0] = *(const float4*)(qp);
    qraw[qt][1] = *(const float4*)(qp + 4);
    qraw[qt][2] = *(const float4*)(qp + 32);
    qraw[qt][3] = *(const float4*)(qp + 36);
  }
  write_kv(false);
  bf16x8 qf[2][2];
#pragma unroll
  for (int qt = 0; qt < 2; qt++) {
#pragma unroll
    for (int h = 0; h < 2; h++) {
      float4 a = qraw[qt][2 * h], b = qraw[qt][2 * h + 1];
      union { u32x4 u; bf16x8 v; } cv;
      cv.u = (u32x4){pack2bf(a.x * FOLD, a.y * FOLD), pack2bf(a.z * FOLD, a.w * FOLD),
                     pack2bf(b.x * FOLD, b.y * FOLD), pack2bf(b.z * FOLD, b.w * FOLD)};
      qf[qt][h] = cv.v;
    }
  }
  __syncthreads();

  f32x4 oA[2][4], oB[2][4];
  float lsA[2] = {0.f, 0.f}, lsB[2] = {0.f, 0.f};
#pragma unroll
  for (int a = 0; a < 2; a++)
#pragma unroll
    for (int b = 0; b < 4; b++) { oA[a][b] = (f32x4){0.f,0.f,0.f,0.f}; oB[a][b] = (f32x4){0.f,0.f,0.f,0.f}; }

  auto phase = [&](f32x4 (&o)[2][4], float (&ls)[2], bool masked) {
#pragma unroll 2
    for (int kt = 0; kt < 8; kt++) {
      const unsigned short* krow = &KsL[(kt * 16 + lr) * PADK + lg * 8];
      bf16x8 ak0 = *(const bf16x8*)(krow);
      bf16x8 ak1 = *(const bf16x8*)(krow + 32);
      bf16x4 av[4];
#pragma unroll
      for (int dt = 0; dt < 4; dt++)
        av[dt] = *(const bf16x4*)(&VtL[(dt * 16 + lr) * PADV + kt * 16 + lg * 4]);
      float msk[4];
      if (masked) {
#pragma unroll
        for (int r = 0; r < 4; r++)
          msk[r] = (sbs[kt * 16 + lg * 4 + r] == blk) ? 0.f : 1.f;
      }
      bf16x4 bq[2];
#pragma unroll
      for (int qt = 0; qt < 2; qt++) {
        f32x4 c = (f32x4){0.f, 0.f, 0.f, 0.f};
        c = __builtin_amdgcn_mfma_f32_16x16x32_bf16(ak0, qf[qt][0], c, 0, 0, 0);
        c = __builtin_amdgcn_mfma_f32_16x16x32_bf16(ak1, qf[qt][1], c, 0, 0, 0);
        float w0 = fexp2(c[0]), w1 = fexp2(c[1]);
        float w2 = fexp2(c[2]), w3 = fexp2(c[3]);
        if (masked) { w0 *= msk[0]; w1 *= msk[1]; w2 *= msk[2]; w3 *= msk[3]; }
        ls[qt] += (w0 + w1) + (w2 + w3);
        union { u32x2 u; bf16x4 v; } cv;
        cv.u = (u32x2){pack2bf(w0, w1), pack2bf(w2, w3)};
        bq[qt] = cv.v;
      }
#pragma unroll
      for (int qt = 0; qt < 2; qt++)
#pragma unroll
        for (int dt = 0; dt < 4; dt++)
          o[qt][dt] = mfma16(av[dt], bq[qt], o[qt][dt]);
    }
  };

  // ---- pipelined chunks: block0, block1, sample0, sample1 ----
  load_block(1);          // issue under phase(block0)
  phase(oA, lsA, false);
  __syncthreads();
  write_kv(false);
  __syncthreads();

  load_sample(0);         // issue under phase(block1)
  phase(oA, lsA, false);
  __syncthreads();
  write_kv(true);
  __syncthreads();

  load_sample(1);         // issue under phase(sample0)
  phase(oB, lsB, true);
  __syncthreads();
  write_kv(true);
  __syncthreads();

  phase(oB, lsB, true);

  // ---- merge + scatter (lane owns q = qt*16+lr, d = dt*16+lg*4..+4) ----
#pragma unroll
  for (int qt = 0; qt < 2; qt++) {
    float lb = lsA[qt];
    lb += __shfl_xor(lb, 16); lb += __shfl_xor(lb, 32);
    float lrv = lsB[qt];
    lrv += __shfl_xor(lrv, 16); lrv += __shfl_xor(lrv, 32);
    float wb, wr;
    float lseb = __logf(lb);
    if (lrv > 0.f) {
      float lser = __logf(lrv) + 3.4657359027997265f;  // + log(32)
      float cc = 1.f / (1.f + __expf(lser - lseb));
      wb = cc / lb; wr = (1.f - cc) / lrv;
    } else {
      wb = 1.f / lb; wr = 0.f;
    }
    float* op = out + ((size_t)bh * N_ + qrw[qt]) * D_ + lg * 4;
#pragma unroll
    for (int dt = 0; dt < 4; dt++) {
      float4 o;
      o.x = wb * oA[qt][dt][0] + wr * oB[qt][dt][0];
      o.y = wb * oA[qt][dt][1] + wr * oB[qt][dt][1];
      o.z = wb * oA[qt][dt][2] + wr * oB[qt][dt][2];
      o.w = wb * oA[qt][dt][3] + wr * oB[qt][dt][3];
      *(float4*)(op + dt * 16) = o;
    }
  }
}

extern "C" void kernel_launch(void* const* d_in, const int* in_sizes, int n_in,
                              void* d_out, int out_size, void* d_ws, size_t ws_size,
                              hipStream_t stream) {
  const float* query = (const float*)d_in[0];
  const float* key   = (const float*)d_in[1];
  const float* value = (const float*)d_in[2];
  const float* pd    = (const float*)d_in[3];
  const int*   samp  = (const int*)d_in[4];
  float* out = (float*)d_out;

  char* w = (char*)d_ws;
  size_t o = 0;
  auto alloc = [&](size_t bytes) { void* p = w + o; o = (o + bytes + 255) & ~(size_t)255; return p; };
  int* qh   = (int*)alloc((size_t)BH_ * N_ * 4);
  int* kh   = (int*)alloc((size_t)BH_ * N_ * 4);
  int* qidx = (int*)alloc((size_t)BH_ * N_ * 4);
  int* kidx = (int*)alloc((size_t)BH_ * N_ * 4);
  float* ksub = (float*)alloc((size_t)BH_ * SAMPLE_ * D_ * 4);
  float* vsub = (float*)alloc((size_t)BH_ * SAMPLE_ * D_ * 4);
  int* sblk = (int*)alloc((size_t)BH_ * SAMPLE_ * 4);

  hash_kernel<<<(2 * BH_ * N_) / 256, 256, 0, stream>>>(query, key, pd, qh, kh);
  sort_kernel<<<2 * BH_, 256, 0, stream>>>(qh, kh, qidx, kidx);
  subgather_kernel<<<BH_ * SAMPLE_ / 4, 256, 0, stream>>>(key, value, kidx, samp, ksub, vsub, sblk);
  attn_kernel<<<BH_ * NBLK_, 512, 0, stream>>>(query, key, value, qidx, kidx,
                                               ksub, vsub, sblk, out);
}

// Round 13
// 126.508 us; speedup vs baseline: 1.0730x; 1.0730x over previous
//
#include <hip/hip_runtime.h>
#include <hip/hip_bf16.h>
#include <math.h>

#define B_ 2
#define H_ 16
#define N_ 8192
#define D_ 64
#define R_ 7
#define BLOCK_ 256
#define SAMPLE_ 256
#define BH_ (B_*H_)
#define NBLK_ (N_/BLOCK_)

#define CHUNK_ 128           // keys staged per chunk
#define PADK 72              // Ks row stride: 144 B
#define PADV 132             // Vt row stride: 264 B

typedef __attribute__((ext_vector_type(8))) short bf16x8;
typedef __attribute__((ext_vector_type(4))) short bf16x4;
typedef __attribute__((ext_vector_type(4))) float f32x4;
typedef __attribute__((ext_vector_type(2))) unsigned int u32x2;
typedef __attribute__((ext_vector_type(4))) unsigned int u32x4;

__device__ inline unsigned short f2bf(float x) {
  __hip_bfloat16 h = __float2bfloat16(x);
  return *(unsigned short*)&h;
}
__device__ inline unsigned int pack2bf(float a, float b) {
  return (unsigned int)f2bf(a) | ((unsigned int)f2bf(b) << 16);
}
__device__ inline float fexp2(float x) {
#if __has_builtin(__builtin_amdgcn_exp2f)
  return __builtin_amdgcn_exp2f(x);
#else
  return exp2f(x);
#endif
}

// PV mfma: D = A(16x16: d x k) * B(16x16: k x q), K=16, bf16
__device__ inline f32x4 mfma16(bf16x4 a, bf16x4 b, f32x4 c) {
#if __has_builtin(__builtin_amdgcn_mfma_f32_16x16x16bf16_1k)
  return __builtin_amdgcn_mfma_f32_16x16x16bf16_1k(a, b, c, 0, 0, 0);
#else
  asm volatile("v_mfma_f32_16x16x16_bf16 %0, %1, %2, %0" : "+v"(c) : "v"(a), "v"(b));
  return c;
#endif
}

// ---------------- Kernel 1: LSH hash (R10 — b128 broadcast spdT) ----------------
__global__ __launch_bounds__(256) void hash_kernel(
    const float* __restrict__ q, const float* __restrict__ k,
    const float* __restrict__ pd, int* __restrict__ qh, int* __restrict__ kh) {
  __shared__ __align__(16) float spdT[R_][D_];   // [r][d]
  for (int i = threadIdx.x; i < D_ * R_; i += blockDim.x) {
    int d = i / R_, r = i - d * R_;              // pd[d*R + r]
    spdT[r][d] = pd[i];
  }
  __syncthreads();
  int tid = blockIdx.x * blockDim.x + threadIdx.x;
  const int half = BH_ * N_;
  const float* src = (tid < half) ? q : k;
  int* dst = (tid < half) ? qh : kh;
  int row = (tid < half) ? tid : tid - half;
  const float4* x4 = (const float4*)(src + (size_t)row * D_);
  float4 x[16];
#pragma unroll
  for (int j = 0; j < 16; j++) x[j] = x4[j];
  int bin = 0;
#pragma unroll
  for (int r = 0; r < R_; r++) {
    float a = 0.f;
#pragma unroll
    for (int j = 0; j < 16; j++) {
      float4 sp = *(const float4*)&spdT[r][4 * j];
      a = fmaf(x[j].x, sp.x, a);
      a = fmaf(x[j].y, sp.y, a);
      a = fmaf(x[j].z, sp.z, a);
      a = fmaf(x[j].w, sp.w, a);
    }
    bin |= (a > 0.f) ? (1 << r) : 0;
  }
  dst[row] = bin ^ (bin >> 1);
}

// ---------------- Kernel 2: stable counting sort + fused sample gather ------------
// 2*BH WGs x 256 threads. Each thread owns 32 consecutive positions.
// K-side WGs additionally gather the sampled K/V rows after the scatter
// (kidx is this WG's own output; hist LDS is reused for sample rows).
__global__ __launch_bounds__(256) void sort_kernel(
    const int* __restrict__ qh, const int* __restrict__ kh,
    int* __restrict__ qidx, int* __restrict__ kidx,
    const float* __restrict__ key, const float* __restrict__ val,
    const int* __restrict__ samp,
    float* __restrict__ ksub, float* __restrict__ vsub, int* __restrict__ sblk) {
  int g = blockIdx.x;
  int bh = g & (BH_ - 1);
  bool isK = g >= BH_;
  const int* h = (isK ? kh : qh) + (size_t)bh * N_;
  int* idx = (isK ? kidx : qidx) + (size_t)bh * N_;
  __shared__ unsigned short hist[128][256];   // 64 KiB
  __shared__ int segsum[128][8];
  __shared__ int tot[128];
  __shared__ int off[128];
  const int t = threadIdx.x;

  {  // zero hist (u32x4 = 16 B stores)
    u32x4* hz = (u32x4*)hist;
    for (int i = t; i < 4096; i += 256) hz[i] = (u32x4){0u, 0u, 0u, 0u};
  }
  __syncthreads();

  const int base = t * 32;
  int hv[32];
#pragma unroll
  for (int j = 0; j < 32; j++) hv[j] = h[base + j];
#pragma unroll
  for (int j = 0; j < 32; j++) hist[hv[j]][t]++;
  __syncthreads();

  for (int task = t; task < 1024; task += 256) {
    int b = task >> 3, s = task & 7;
    int sum = 0;
#pragma unroll
    for (int u = 0; u < 32; u++) sum += hist[b][s * 32 + u];
    segsum[b][s] = sum;
  }
  __syncthreads();

  if (t < 128) {
    int run = 0;
#pragma unroll
    for (int s = 0; s < 8; s++) { int x = segsum[t][s]; segsum[t][s] = run; run += x; }
    tot[t] = run;
  }
  __syncthreads();

  if (t == 0) {
    int run = 0;
    for (int b = 0; b < 128; b++) { off[b] = run; run += tot[b]; }
  }
  __syncthreads();

  for (int task = t; task < 1024; task += 256) {
    int b = task >> 3, s = task & 7;
    int run = off[b] + segsum[b][s];
#pragma unroll
    for (int u = 0; u < 32; u++) {
      int x = hist[b][s * 32 + u];
      hist[b][s * 32 + u] = (unsigned short)run;
      run += x;
    }
  }
  __syncthreads();

#pragma unroll
  for (int j = 0; j < 32; j++) {
    int c = hv[j];
    int p = hist[c][t]++;
    idx[p] = base + j;
  }

  // ---- fused subgather (K-side WGs only) ----
  if (isK) {
    __syncthreads();                       // all idx writes done (drained by barrier)
    int* srows = (int*)hist;               // reuse hist LDS for sample rows
    int pos = samp[(size_t)bh * SAMPLE_ + t];
    int row = idx[pos];                    // own WG's output, same-CU L1/L2
    srows[t] = row;
    sblk[(size_t)bh * SAMPLE_ + t] = pos >> 8;   // BLOCK_=256
    __syncthreads();
    const int d = t & 63;
    for (int it = 0; it < 64; it++) {      // 4 samples x 64 lanes per iteration
      int s = it * 4 + (t >> 6);
      int r = srows[s];
      ksub[((size_t)bh * SAMPLE_ + s) * D_ + d] = key[((size_t)bh * N_ + r) * D_ + d];
      vsub[((size_t)bh * SAMPLE_ + s) * D_ + d] = val[((size_t)bh * N_ + r) * D_ + d];
    }
  }
}

// ---------------- Kernel 4: MFMA fused attention (R11 structure + setprio) --------
__global__ __launch_bounds__(512, 4) void attn_kernel(
    const float* __restrict__ query, const float* __restrict__ key,
    const float* __restrict__ value,
    const int* __restrict__ qidx, const int* __restrict__ kidx,
    const float* __restrict__ ksub, const float* __restrict__ vsub,
    const int* __restrict__ sblk, float* __restrict__ out) {
  __shared__ __align__(16) unsigned short KsL[CHUNK_ * PADK];   // 18432 B
  __shared__ __align__(16) unsigned short VtL[D_ * PADV];       // 16896 B
  __shared__ int sbs[CHUNK_];
  __shared__ int qrows[BLOCK_];

  const int bh = blockIdx.x / NBLK_;
  const int blk = blockIdx.x - bh * NBLK_;
  const int tid = threadIdx.x;
  const int w = tid >> 6;       // wave 0..7
  const int lane = tid & 63;
  const int lg = lane >> 4;
  const int lr = lane & 15;
  const float FOLD = 0.18033688011112042f;   // (1/8) * log2(e)

  // ---- staging: thread -> (k-pair kp 0..63, d-octant dq 0..7) ----
  const int kp = tid >> 3, dq = tid & 7;
  auto stage_kv = [&](const float* kr0, const float* kr1,
                      const float* vr0, const float* vr1, int kbase) {
    float4 ka0 = *(const float4*)(kr0), ka1 = *(const float4*)(kr0 + 4);
    float4 kb0 = *(const float4*)(kr1), kb1 = *(const float4*)(kr1 + 4);
    u32x4 pk0 = (u32x4){pack2bf(ka0.x, ka0.y), pack2bf(ka0.z, ka0.w),
                        pack2bf(ka1.x, ka1.y), pack2bf(ka1.z, ka1.w)};
    u32x4 pk1 = (u32x4){pack2bf(kb0.x, kb0.y), pack2bf(kb0.z, kb0.w),
                        pack2bf(kb1.x, kb1.y), pack2bf(kb1.z, kb1.w)};
    *(u32x4*)&KsL[(kbase + 0) * PADK + dq * 8] = pk0;
    *(u32x4*)&KsL[(kbase + 1) * PADK + dq * 8] = pk1;
    float4 va0 = *(const float4*)(vr0), va1 = *(const float4*)(vr0 + 4);
    float4 vb0 = *(const float4*)(vr1), vb1 = *(const float4*)(vr1 + 4);
    float a[8] = {va0.x, va0.y, va0.z, va0.w, va1.x, va1.y, va1.z, va1.w};
    float b[8] = {vb0.x, vb0.y, vb0.z, vb0.w, vb1.x, vb1.y, vb1.z, vb1.w};
#pragma unroll
    for (int j = 0; j < 8; j++)
      *(unsigned*)&VtL[(dq * 8 + j) * PADV + kbase] = pack2bf(a[j], b[j]);
  };
  auto stage_block = [&](int c) {
    size_t ib = (size_t)bh * N_ + blk * BLOCK_ + c * CHUNK_ + 2 * kp;
    int r0 = kidx[ib], r1 = kidx[ib + 1];
    const float* k0 = key + ((size_t)bh * N_ + r0) * D_ + dq * 8;
    const float* k1 = key + ((size_t)bh * N_ + r1) * D_ + dq * 8;
    const float* v0 = value + ((size_t)bh * N_ + r0) * D_ + dq * 8;
    const float* v1 = value + ((size_t)bh * N_ + r1) * D_ + dq * 8;
    stage_kv(k0, k1, v0, v1, 2 * kp);
  };
  auto stage_sample = [&](int c) {
    size_t b0 = ((size_t)bh * SAMPLE_ + c * CHUNK_ + 2 * kp) * D_ + dq * 8;
    stage_kv(ksub + b0, ksub + b0 + D_, vsub + b0, vsub + b0 + D_, 2 * kp);
    if (tid < CHUNK_) sbs[tid] = sblk[(size_t)bh * SAMPLE_ + c * CHUNK_ + tid];
  };

  // ---- first chunk + qrows ----
  stage_block(0);
  if (tid < BLOCK_) qrows[tid] = qidx[(size_t)bh * N_ + blk * BLOCK_ + tid];
  __syncthreads();

  // ---- Q fragments (scale folded): lane holds Q[q=qt*16+lr][d=lg*8+h*32..+8] ----
  bf16x8 qf[2][2];
#pragma unroll
  for (int qt = 0; qt < 2; qt++) {
    int qrow = qrows[w * 32 + qt * 16 + lr];
    const float* qp = query + ((size_t)bh * N_ + qrow) * D_ + lg * 8;
#pragma unroll
    for (int h = 0; h < 2; h++) {
      float4 a = *(const float4*)(qp + h * 32);
      float4 b = *(const float4*)(qp + h * 32 + 4);
      union { u32x4 u; bf16x8 v; } cv;
      cv.u = (u32x4){pack2bf(a.x * FOLD, a.y * FOLD), pack2bf(a.z * FOLD, a.w * FOLD),
                     pack2bf(b.x * FOLD, b.y * FOLD), pack2bf(b.z * FOLD, b.w * FOLD)};
      qf[qt][h] = cv.v;
    }
  }

  f32x4 oA[2][4], oB[2][4];
  float lsA[2] = {0.f, 0.f}, lsB[2] = {0.f, 0.f};
#pragma unroll
  for (int a = 0; a < 2; a++)
#pragma unroll
    for (int b = 0; b < 4; b++) { oA[a][b] = (f32x4){0.f,0.f,0.f,0.f}; oB[a][b] = (f32x4){0.f,0.f,0.f,0.f}; }

  auto phase = [&](f32x4 (&o)[2][4], float (&ls)[2], bool masked) {
    __builtin_amdgcn_s_setprio(1);   // T5: favor MFMA-issuing wave vs staging waves
#pragma unroll 2
    for (int kt = 0; kt < 8; kt++) {
      const unsigned short* krow = &KsL[(kt * 16 + lr) * PADK + lg * 8];
      bf16x8 ak0 = *(const bf16x8*)(krow);
      bf16x8 ak1 = *(const bf16x8*)(krow + 32);
      bf16x4 av[4];
#pragma unroll
      for (int dt = 0; dt < 4; dt++)
        av[dt] = *(const bf16x4*)(&VtL[(dt * 16 + lr) * PADV + kt * 16 + lg * 4]);
      float msk[4];
      if (masked) {
#pragma unroll
        for (int r = 0; r < 4; r++)
          msk[r] = (sbs[kt * 16 + lg * 4 + r] == blk) ? 0.f : 1.f;
      }
      bf16x4 bq[2];
#pragma unroll
      for (int qt = 0; qt < 2; qt++) {
        f32x4 c = (f32x4){0.f, 0.f, 0.f, 0.f};
        c = __builtin_amdgcn_mfma_f32_16x16x32_bf16(ak0, qf[qt][0], c, 0, 0, 0);
        c = __builtin_amdgcn_mfma_f32_16x16x32_bf16(ak1, qf[qt][1], c, 0, 0, 0);
        float w0 = fexp2(c[0]), w1 = fexp2(c[1]);
        float w2 = fexp2(c[2]), w3 = fexp2(c[3]);
        if (masked) { w0 *= msk[0]; w1 *= msk[1]; w2 *= msk[2]; w3 *= msk[3]; }
        ls[qt] += (w0 + w1) + (w2 + w3);
        union { u32x2 u; bf16x4 v; } cv;
        cv.u = (u32x2){pack2bf(w0, w1), pack2bf(w2, w3)};
        bq[qt] = cv.v;
      }
#pragma unroll
      for (int qt = 0; qt < 2; qt++)
#pragma unroll
        for (int dt = 0; dt < 4; dt++)
          o[qt][dt] = mfma16(av[dt], bq[qt], o[qt][dt]);
    }
    __builtin_amdgcn_s_setprio(0);
  };

  phase(oA, lsA, false);
  __syncthreads();
  stage_block(1);
  __syncthreads();
  phase(oA, lsA, false);
  __syncthreads();

  stage_sample(0);
  __syncthreads();
  phase(oB, lsB, true);
  __syncthreads();
  stage_sample(1);
  __syncthreads();
  phase(oB, lsB, true);

  // ---- merge + scatter (lane owns q = qt*16+lr, d = dt*16+lg*4..+4) ----
#pragma unroll
  for (int qt = 0; qt < 2; qt++) {
    float lb = lsA[qt];
    lb += __shfl_xor(lb, 16); lb += __shfl_xor(lb, 32);
    float lrv = lsB[qt];
    lrv += __shfl_xor(lrv, 16); lrv += __shfl_xor(lrv, 32);
    float wb, wr;
    float lseb = __logf(lb);
    if (lrv > 0.f) {
      float lser = __logf(lrv) + 3.4657359027997265f;  // + log(32)
      float cc = 1.f / (1.f + __expf(lser - lseb));
      wb = cc / lb; wr = (1.f - cc) / lrv;
    } else {
      wb = 1.f / lb; wr = 0.f;
    }
    int qr = qrows[w * 32 + qt * 16 + lr];
    float* op = out + ((size_t)bh * N_ + qr) * D_ + lg * 4;
#pragma unroll
    for (int dt = 0; dt < 4; dt++) {
      float4 o;
      o.x = wb * oA[qt][dt][0] + wr * oB[qt][dt][0];
      o.y = wb * oA[qt][dt][1] + wr * oB[qt][dt][1];
      o.z = wb * oA[qt][dt][2] + wr * oB[qt][dt][2];
      o.w = wb * oA[qt][dt][3] + wr * oB[qt][dt][3];
      *(float4*)(op + dt * 16) = o;
    }
  }
}

extern "C" void kernel_launch(void* const* d_in, const int* in_sizes, int n_in,
                              void* d_out, int out_size, void* d_ws, size_t ws_size,
                              hipStream_t stream) {
  const float* query = (const float*)d_in[0];
  const float* key   = (const float*)d_in[1];
  const float* value = (const float*)d_in[2];
  const float* pd    = (const float*)d_in[3];
  const int*   samp  = (const int*)d_in[4];
  float* out = (float*)d_out;

  char* w = (char*)d_ws;
  size_t o = 0;
  auto alloc = [&](size_t bytes) { void* p = w + o; o = (o + bytes + 255) & ~(size_t)255; return p; };
  int* qh   = (int*)alloc((size_t)BH_ * N_ * 4);
  int* kh   = (int*)alloc((size_t)BH_ * N_ * 4);
  int* qidx = (int*)alloc((size_t)BH_ * N_ * 4);
  int* kidx = (int*)alloc((size_t)BH_ * N_ * 4);
  float* ksub = (float*)alloc((size_t)BH_ * SAMPLE_ * D_ * 4);
  float* vsub = (float*)alloc((size_t)BH_ * SAMPLE_ * D_ * 4);
  int* sblk = (int*)alloc((size_t)BH_ * SAMPLE_ * 4);

  hash_kernel<<<(2 * BH_ * N_) / 256, 256, 0, stream>>>(query, key, pd, qh, kh);
  sort_kernel<<<2 * BH_, 256, 0, stream>>>(qh, kh, qidx, kidx,
                                           key, value, samp, ksub, vsub, sblk);
  attn_kernel<<<BH_ * NBLK_, 512, 0, stream>>>(query, key, value, qidx, kidx,
                                               ksub, vsub, sblk, out);
}

// Round 14
// 116.295 us; speedup vs baseline: 1.1672x; 1.0878x over previous
//
#include <hip/hip_runtime.h>
#include <hip/hip_bf16.h>
#include <math.h>

#define B_ 2
#define H_ 16
#define N_ 8192
#define D_ 64
#define R_ 7
#define BLOCK_ 256
#define SAMPLE_ 256
#define BH_ (B_*H_)
#define NBLK_ (N_/BLOCK_)

#define CHUNK_ 128           // keys staged per chunk
#define PADK 72              // Ks row stride: 144 B
#define PADV 132             // Vt row stride: 264 B

typedef __attribute__((ext_vector_type(8))) short bf16x8;
typedef __attribute__((ext_vector_type(4))) short bf16x4;
typedef __attribute__((ext_vector_type(4))) float f32x4;
typedef __attribute__((ext_vector_type(2))) unsigned int u32x2;
typedef __attribute__((ext_vector_type(4))) unsigned int u32x4;

__device__ inline unsigned short f2bf(float x) {
  __hip_bfloat16 h = __float2bfloat16(x);
  return *(unsigned short*)&h;
}
__device__ inline unsigned int pack2bf(float a, float b) {
  return (unsigned int)f2bf(a) | ((unsigned int)f2bf(b) << 16);
}
__device__ inline float fexp2(float x) {
#if __has_builtin(__builtin_amdgcn_exp2f)
  return __builtin_amdgcn_exp2f(x);
#else
  return exp2f(x);
#endif
}

// PV mfma: D = A(16x16: d x k) * B(16x16: k x q), K=16, bf16
__device__ inline f32x4 mfma16(bf16x4 a, bf16x4 b, f32x4 c) {
#if __has_builtin(__builtin_amdgcn_mfma_f32_16x16x16bf16_1k)
  return __builtin_amdgcn_mfma_f32_16x16x16bf16_1k(a, b, c, 0, 0, 0);
#else
  asm volatile("v_mfma_f32_16x16x16_bf16 %0, %1, %2, %0" : "+v"(c) : "v"(a), "v"(b));
  return c;
#endif
}

// ---------------- Kernel 1: LSH hash (R10 — b128 broadcast spdT) ----------------
__global__ __launch_bounds__(256) void hash_kernel(
    const float* __restrict__ q, const float* __restrict__ k,
    const float* __restrict__ pd, int* __restrict__ qh, int* __restrict__ kh) {
  __shared__ __align__(16) float spdT[R_][D_];   // [r][d]
  for (int i = threadIdx.x; i < D_ * R_; i += blockDim.x) {
    int d = i / R_, r = i - d * R_;              // pd[d*R + r]
    spdT[r][d] = pd[i];
  }
  __syncthreads();
  int tid = blockIdx.x * blockDim.x + threadIdx.x;
  const int half = BH_ * N_;
  const float* src = (tid < half) ? q : k;
  int* dst = (tid < half) ? qh : kh;
  int row = (tid < half) ? tid : tid - half;
  const float4* x4 = (const float4*)(src + (size_t)row * D_);
  float4 x[16];
#pragma unroll
  for (int j = 0; j < 16; j++) x[j] = x4[j];
  int bin = 0;
#pragma unroll
  for (int r = 0; r < R_; r++) {
    float a = 0.f;
#pragma unroll
    for (int j = 0; j < 16; j++) {
      float4 sp = *(const float4*)&spdT[r][4 * j];
      a = fmaf(x[j].x, sp.x, a);
      a = fmaf(x[j].y, sp.y, a);
      a = fmaf(x[j].z, sp.z, a);
      a = fmaf(x[j].w, sp.w, a);
    }
    bin |= (a > 0.f) ? (1 << r) : 0;
  }
  dst[row] = bin ^ (bin >> 1);
}

// ---------------- Kernel 2: stable counting sort, 256 threads/WG (R10 — unfused) ----
__global__ __launch_bounds__(256) void sort_kernel(
    const int* __restrict__ qh, const int* __restrict__ kh,
    int* __restrict__ qidx, int* __restrict__ kidx) {
  int g = blockIdx.x;
  int bh = g & (BH_ - 1);
  bool isK = g >= BH_;
  const int* h = (isK ? kh : qh) + (size_t)bh * N_;
  int* idx = (isK ? kidx : qidx) + (size_t)bh * N_;
  __shared__ unsigned short hist[128][256];   // 64 KiB
  __shared__ int segsum[128][8];
  __shared__ int tot[128];
  __shared__ int off[128];
  const int t = threadIdx.x;

  {  // zero hist (u32x4 = 16 B stores)
    u32x4* hz = (u32x4*)hist;
    for (int i = t; i < 4096; i += 256) hz[i] = (u32x4){0u, 0u, 0u, 0u};
  }
  __syncthreads();

  const int base = t * 32;
  int hv[32];
#pragma unroll
  for (int j = 0; j < 32; j++) hv[j] = h[base + j];
#pragma unroll
  for (int j = 0; j < 32; j++) hist[hv[j]][t]++;
  __syncthreads();

  for (int task = t; task < 1024; task += 256) {
    int b = task >> 3, s = task & 7;
    int sum = 0;
#pragma unroll
    for (int u = 0; u < 32; u++) sum += hist[b][s * 32 + u];
    segsum[b][s] = sum;
  }
  __syncthreads();

  if (t < 128) {
    int run = 0;
#pragma unroll
    for (int s = 0; s < 8; s++) { int x = segsum[t][s]; segsum[t][s] = run; run += x; }
    tot[t] = run;
  }
  __syncthreads();

  if (t == 0) {
    int run = 0;
    for (int b = 0; b < 128; b++) { off[b] = run; run += tot[b]; }
  }
  __syncthreads();

  for (int task = t; task < 1024; task += 256) {
    int b = task >> 3, s = task & 7;
    int run = off[b] + segsum[b][s];
#pragma unroll
    for (int u = 0; u < 32; u++) {
      int x = hist[b][s * 32 + u];
      hist[b][s * 32 + u] = (unsigned short)run;
      run += x;
    }
  }
  __syncthreads();

#pragma unroll
  for (int j = 0; j < 32; j++) {
    int c = hv[j];
    int p = hist[c][t]++;
    idx[p] = base + j;
  }
}

// ---------------- Kernel 3: gather sampled K/V (256-thread blocks, separate) -------
__global__ __launch_bounds__(256) void subgather_kernel(
    const float* __restrict__ key, const float* __restrict__ val,
    const int* __restrict__ kidx, const int* __restrict__ samp,
    float* __restrict__ ksub, float* __restrict__ vsub, int* __restrict__ sblk) {
  int sidx = blockIdx.x * 4 + (threadIdx.x >> 6);   // 0 .. BH*SAMPLE-1
  int bh = sidx >> 8;                                // SAMPLE_=256
  int d = threadIdx.x & 63;
  int pos = samp[sidx];
  int row = kidx[(size_t)bh * N_ + pos];
  ksub[(size_t)sidx * D_ + d] = key[((size_t)bh * N_ + row) * D_ + d];
  vsub[(size_t)sidx * D_ + d] = val[((size_t)bh * N_ + row) * D_ + d];
  if (d == 0) sblk[sidx] = pos >> 8;                 // BLOCK_=256
}

// ---------------- Kernel 4: MFMA fused attention — LINEAR MERGE ----------------
// Identity: out = (oA + 32*oB) / (lb + 32*lr)   [c=sigmoid(lseA-lseB) merge is linear]
// -> ONE accumulator set; phase-B weights pre-scaled by 32 (mask value 32.0,
//    exact exponent shift in bf16). Halves accumulator AGPRs (64->32) ->
//    footprint ~96 regs -> 4 waves/SIMD under (512,4). Epilogue = reduce + rcp.
__global__ __launch_bounds__(512, 4) void attn_kernel(
    const float* __restrict__ query, const float* __restrict__ key,
    const float* __restrict__ value,
    const int* __restrict__ qidx, const int* __restrict__ kidx,
    const float* __restrict__ ksub, const float* __restrict__ vsub,
    const int* __restrict__ sblk, float* __restrict__ out) {
  __shared__ __align__(16) unsigned short KsL[CHUNK_ * PADK];   // 18432 B
  __shared__ __align__(16) unsigned short VtL[D_ * PADV];       // 16896 B
  __shared__ int sbs[CHUNK_];
  __shared__ int qrows[BLOCK_];

  const int bh = blockIdx.x / NBLK_;
  const int blk = blockIdx.x - bh * NBLK_;
  const int tid = threadIdx.x;
  const int w = tid >> 6;       // wave 0..7
  const int lane = tid & 63;
  const int lg = lane >> 4;
  const int lr = lane & 15;
  const float FOLD = 0.18033688011112042f;   // (1/8) * log2(e)

  // ---- staging: thread -> (k-pair kp 0..63, d-octant dq 0..7) ----
  const int kp = tid >> 3, dq = tid & 7;
  auto stage_kv = [&](const float* kr0, const float* kr1,
                      const float* vr0, const float* vr1, int kbase) {
    float4 ka0 = *(const float4*)(kr0), ka1 = *(const float4*)(kr0 + 4);
    float4 kb0 = *(const float4*)(kr1), kb1 = *(const float4*)(kr1 + 4);
    u32x4 pk0 = (u32x4){pack2bf(ka0.x, ka0.y), pack2bf(ka0.z, ka0.w),
                        pack2bf(ka1.x, ka1.y), pack2bf(ka1.z, ka1.w)};
    u32x4 pk1 = (u32x4){pack2bf(kb0.x, kb0.y), pack2bf(kb0.z, kb0.w),
                        pack2bf(kb1.x, kb1.y), pack2bf(kb1.z, kb1.w)};
    *(u32x4*)&KsL[(kbase + 0) * PADK + dq * 8] = pk0;
    *(u32x4*)&KsL[(kbase + 1) * PADK + dq * 8] = pk1;
    float4 va0 = *(const float4*)(vr0), va1 = *(const float4*)(vr0 + 4);
    float4 vb0 = *(const float4*)(vr1), vb1 = *(const float4*)(vr1 + 4);
    float a[8] = {va0.x, va0.y, va0.z, va0.w, va1.x, va1.y, va1.z, va1.w};
    float b[8] = {vb0.x, vb0.y, vb0.z, vb0.w, vb1.x, vb1.y, vb1.z, vb1.w};
#pragma unroll
    for (int j = 0; j < 8; j++)
      *(unsigned*)&VtL[(dq * 8 + j) * PADV + kbase] = pack2bf(a[j], b[j]);
  };
  auto stage_block = [&](int c) {
    size_t ib = (size_t)bh * N_ + blk * BLOCK_ + c * CHUNK_ + 2 * kp;
    int r0 = kidx[ib], r1 = kidx[ib + 1];
    const float* k0 = key + ((size_t)bh * N_ + r0) * D_ + dq * 8;
    const float* k1 = key + ((size_t)bh * N_ + r1) * D_ + dq * 8;
    const float* v0 = value + ((size_t)bh * N_ + r0) * D_ + dq * 8;
    const float* v1 = value + ((size_t)bh * N_ + r1) * D_ + dq * 8;
    stage_kv(k0, k1, v0, v1, 2 * kp);
  };
  auto stage_sample = [&](int c) {
    size_t b0 = ((size_t)bh * SAMPLE_ + c * CHUNK_ + 2 * kp) * D_ + dq * 8;
    stage_kv(ksub + b0, ksub + b0 + D_, vsub + b0, vsub + b0 + D_, 2 * kp);
    if (tid < CHUNK_) sbs[tid] = sblk[(size_t)bh * SAMPLE_ + c * CHUNK_ + tid];
  };

  // ---- first chunk + qrows ----
  stage_block(0);
  if (tid < BLOCK_) qrows[tid] = qidx[(size_t)bh * N_ + blk * BLOCK_ + tid];
  __syncthreads();

  // ---- Q fragments (scale folded): lane holds Q[q=qt*16+lr][d=lg*8+h*32..+8] ----
  bf16x8 qf[2][2];
#pragma unroll
  for (int qt = 0; qt < 2; qt++) {
    int qrow = qrows[w * 32 + qt * 16 + lr];
    const float* qp = query + ((size_t)bh * N_ + qrow) * D_ + lg * 8;
#pragma unroll
    for (int h = 0; h < 2; h++) {
      float4 a = *(const float4*)(qp + h * 32);
      float4 b = *(const float4*)(qp + h * 32 + 4);
      union { u32x4 u; bf16x8 v; } cv;
      cv.u = (u32x4){pack2bf(a.x * FOLD, a.y * FOLD), pack2bf(a.z * FOLD, a.w * FOLD),
                     pack2bf(b.x * FOLD, b.y * FOLD), pack2bf(b.z * FOLD, b.w * FOLD)};
      qf[qt][h] = cv.v;
    }
  }

  // ---- SINGLE accumulator set (linear merge) ----
  f32x4 oX[2][4];
  float ls[2] = {0.f, 0.f};
#pragma unroll
  for (int a = 0; a < 2; a++)
#pragma unroll
    for (int b = 0; b < 4; b++) oX[a][b] = (f32x4){0.f, 0.f, 0.f, 0.f};

  // masked phases: weight = 32 * exp2(s) (importance factor folded into mask value)
  auto phase = [&](bool masked) {
    __builtin_amdgcn_s_setprio(1);
#pragma unroll 2
    for (int kt = 0; kt < 8; kt++) {
      const unsigned short* krow = &KsL[(kt * 16 + lr) * PADK + lg * 8];
      bf16x8 ak0 = *(const bf16x8*)(krow);
      bf16x8 ak1 = *(const bf16x8*)(krow + 32);
      bf16x4 av[4];
#pragma unroll
      for (int dt = 0; dt < 4; dt++)
        av[dt] = *(const bf16x4*)(&VtL[(dt * 16 + lr) * PADV + kt * 16 + lg * 4]);
      float msk[4];
      if (masked) {
#pragma unroll
        for (int r = 0; r < 4; r++)
          msk[r] = (sbs[kt * 16 + lg * 4 + r] == blk) ? 0.f : 32.f;   // 32 = N/SAMPLE
      }
      bf16x4 bq[2];
#pragma unroll
      for (int qt = 0; qt < 2; qt++) {
        f32x4 c = (f32x4){0.f, 0.f, 0.f, 0.f};
        c = __builtin_amdgcn_mfma_f32_16x16x32_bf16(ak0, qf[qt][0], c, 0, 0, 0);
        c = __builtin_amdgcn_mfma_f32_16x16x32_bf16(ak1, qf[qt][1], c, 0, 0, 0);
        float w0 = fexp2(c[0]), w1 = fexp2(c[1]);
        float w2 = fexp2(c[2]), w3 = fexp2(c[3]);
        if (masked) { w0 *= msk[0]; w1 *= msk[1]; w2 *= msk[2]; w3 *= msk[3]; }
        ls[qt] += (w0 + w1) + (w2 + w3);
        union { u32x2 u; bf16x4 v; } cv;
        cv.u = (u32x2){pack2bf(w0, w1), pack2bf(w2, w3)};
        bq[qt] = cv.v;
      }
#pragma unroll
      for (int qt = 0; qt < 2; qt++)
#pragma unroll
        for (int dt = 0; dt < 4; dt++)
          oX[qt][dt] = mfma16(av[dt], bq[qt], oX[qt][dt]);
    }
    __builtin_amdgcn_s_setprio(0);
  };

  phase(false);
  __syncthreads();
  stage_block(1);
  __syncthreads();
  phase(false);
  __syncthreads();

  stage_sample(0);
  __syncthreads();
  phase(true);
  __syncthreads();
  stage_sample(1);
  __syncthreads();
  phase(true);

  // ---- normalize + scatter: out = oX / ls ----
#pragma unroll
  for (int qt = 0; qt < 2; qt++) {
    float l = ls[qt];
    l += __shfl_xor(l, 16); l += __shfl_xor(l, 32);
    float winv = 1.f / l;
    int qr = qrows[w * 32 + qt * 16 + lr];
    float* op = out + ((size_t)bh * N_ + qr) * D_ + lg * 4;
#pragma unroll
    for (int dt = 0; dt < 4; dt++) {
      float4 o;
      o.x = winv * oX[qt][dt][0];
      o.y = winv * oX[qt][dt][1];
      o.z = winv * oX[qt][dt][2];
      o.w = winv * oX[qt][dt][3];
      *(float4*)(op + dt * 16) = o;
    }
  }
}

extern "C" void kernel_launch(void* const* d_in, const int* in_sizes, int n_in,
                              void* d_out, int out_size, void* d_ws, size_t ws_size,
                              hipStream_t stream) {
  const float* query = (const float*)d_in[0];
  const float* key   = (const float*)d_in[1];
  const float* value = (const float*)d_in[2];
  const float* pd    = (const float*)d_in[3];
  const int*   samp  = (const int*)d_in[4];
  float* out = (float*)d_out;

  char* w = (char*)d_ws;
  size_t o = 0;
  auto alloc = [&](size_t bytes) { void* p = w + o; o = (o + bytes + 255) & ~(size_t)255; return p; };
  int* qh   = (int*)alloc((size_t)BH_ * N_ * 4);
  int* kh   = (int*)alloc((size_t)BH_ * N_ * 4);
  int* qidx = (int*)alloc((size_t)BH_ * N_ * 4);
  int* kidx = (int*)alloc((size_t)BH_ * N_ * 4);
  float* ksub = (float*)alloc((size_t)BH_ * SAMPLE_ * D_ * 4);
  float* vsub = (float*)alloc((size_t)BH_ * SAMPLE_ * D_ * 4);
  int* sblk = (int*)alloc((size_t)BH_ * SAMPLE_ * 4);

  hash_kernel<<<(2 * BH_ * N_) / 256, 256, 0, stream>>>(query, key, pd, qh, kh);
  sort_kernel<<<2 * BH_, 256, 0, stream>>>(qh, kh, qidx, kidx);
  subgather_kernel<<<BH_ * SAMPLE_ / 4, 256, 0, stream>>>(key, value, kidx, samp, ksub, vsub, sblk);
  attn_kernel<<<BH_ * NBLK_, 512, 0, stream>>>(query, key, value, qidx, kidx,
                                               ksub, vsub, sblk, out);
}

// Round 15
// 115.731 us; speedup vs baseline: 1.1729x; 1.0049x over previous
//
#include <hip/hip_runtime.h>
#include <hip/hip_bf16.h>
#include <math.h>

#define B_ 2
#define H_ 16
#define N_ 8192
#define D_ 64
#define R_ 7
#define BLOCK_ 256
#define SAMPLE_ 256
#define BH_ (B_*H_)
#define NBLK_ (N_/BLOCK_)

#define CHUNK_ 128           // keys staged per chunk
#define PADK 72              // Ks row stride: 144 B
#define PADV 132             // Vt row stride: 264 B

typedef __attribute__((ext_vector_type(8))) short bf16x8;
typedef __attribute__((ext_vector_type(4))) short bf16x4;
typedef __attribute__((ext_vector_type(4))) float f32x4;
typedef __attribute__((ext_vector_type(2))) unsigned int u32x2;
typedef __attribute__((ext_vector_type(4))) unsigned int u32x4;

__device__ inline unsigned short f2bf(float x) {
  __hip_bfloat16 h = __float2bfloat16(x);
  return *(unsigned short*)&h;
}
__device__ inline unsigned int pack2bf(float a, float b) {
  return (unsigned int)f2bf(a) | ((unsigned int)f2bf(b) << 16);
}
__device__ inline float fexp2(float x) {
#if __has_builtin(__builtin_amdgcn_exp2f)
  return __builtin_amdgcn_exp2f(x);
#else
  return exp2f(x);
#endif
}

// PV mfma: D = A(16x16: d x k) * B(16x16: k x q), K=16, bf16
__device__ inline f32x4 mfma16(bf16x4 a, bf16x4 b, f32x4 c) {
#if __has_builtin(__builtin_amdgcn_mfma_f32_16x16x16bf16_1k)
  return __builtin_amdgcn_mfma_f32_16x16x16bf16_1k(a, b, c, 0, 0, 0);
#else
  asm volatile("v_mfma_f32_16x16x16_bf16 %0, %1, %2, %0" : "+v"(c) : "v"(a), "v"(b));
  return c;
#endif
}

// ---------------- Kernel 1: LSH hash (R10 — b128 broadcast spdT) ----------------
__global__ __launch_bounds__(256) void hash_kernel(
    const float* __restrict__ q, const float* __restrict__ k,
    const float* __restrict__ pd, int* __restrict__ qh, int* __restrict__ kh) {
  __shared__ __align__(16) float spdT[R_][D_];   // [r][d]
  for (int i = threadIdx.x; i < D_ * R_; i += blockDim.x) {
    int d = i / R_, r = i - d * R_;              // pd[d*R + r]
    spdT[r][d] = pd[i];
  }
  __syncthreads();
  int tid = blockIdx.x * blockDim.x + threadIdx.x;
  const int half = BH_ * N_;
  const float* src = (tid < half) ? q : k;
  int* dst = (tid < half) ? qh : kh;
  int row = (tid < half) ? tid : tid - half;
  const float4* x4 = (const float4*)(src + (size_t)row * D_);
  float4 x[16];
#pragma unroll
  for (int j = 0; j < 16; j++) x[j] = x4[j];
  int bin = 0;
#pragma unroll
  for (int r = 0; r < R_; r++) {
    float a = 0.f;
#pragma unroll
    for (int j = 0; j < 16; j++) {
      float4 sp = *(const float4*)&spdT[r][4 * j];
      a = fmaf(x[j].x, sp.x, a);
      a = fmaf(x[j].y, sp.y, a);
      a = fmaf(x[j].z, sp.z, a);
      a = fmaf(x[j].w, sp.w, a);
    }
    bin |= (a > 0.f) ? (1 << r) : 0;
  }
  dst[row] = bin ^ (bin >> 1);
}

// ---------------- Kernel 2: stable counting sort, 256 threads/WG (R10) ----------------
__global__ __launch_bounds__(256) void sort_kernel(
    const int* __restrict__ qh, const int* __restrict__ kh,
    int* __restrict__ qidx, int* __restrict__ kidx) {
  int g = blockIdx.x;
  int bh = g & (BH_ - 1);
  bool isK = g >= BH_;
  const int* h = (isK ? kh : qh) + (size_t)bh * N_;
  int* idx = (isK ? kidx : qidx) + (size_t)bh * N_;
  __shared__ unsigned short hist[128][256];   // 64 KiB
  __shared__ int segsum[128][8];
  __shared__ int tot[128];
  __shared__ int off[128];
  const int t = threadIdx.x;

  {  // zero hist (u32x4 = 16 B stores)
    u32x4* hz = (u32x4*)hist;
    for (int i = t; i < 4096; i += 256) hz[i] = (u32x4){0u, 0u, 0u, 0u};
  }
  __syncthreads();

  const int base = t * 32;
  int hv[32];
#pragma unroll
  for (int j = 0; j < 32; j++) hv[j] = h[base + j];
#pragma unroll
  for (int j = 0; j < 32; j++) hist[hv[j]][t]++;
  __syncthreads();

  for (int task = t; task < 1024; task += 256) {
    int b = task >> 3, s = task & 7;
    int sum = 0;
#pragma unroll
    for (int u = 0; u < 32; u++) sum += hist[b][s * 32 + u];
    segsum[b][s] = sum;
  }
  __syncthreads();

  if (t < 128) {
    int run = 0;
#pragma unroll
    for (int s = 0; s < 8; s++) { int x = segsum[t][s]; segsum[t][s] = run; run += x; }
    tot[t] = run;
  }
  __syncthreads();

  if (t == 0) {
    int run = 0;
    for (int b = 0; b < 128; b++) { off[b] = run; run += tot[b]; }
  }
  __syncthreads();

  for (int task = t; task < 1024; task += 256) {
    int b = task >> 3, s = task & 7;
    int run = off[b] + segsum[b][s];
#pragma unroll
    for (int u = 0; u < 32; u++) {
      int x = hist[b][s * 32 + u];
      hist[b][s * 32 + u] = (unsigned short)run;
      run += x;
    }
  }
  __syncthreads();

#pragma unroll
  for (int j = 0; j < 32; j++) {
    int c = hv[j];
    int p = hist[c][t]++;
    idx[p] = base + j;
  }
}

// ---------------- Kernel 3: gather sampled K/V (256-thread blocks) ----------------
__global__ __launch_bounds__(256) void subgather_kernel(
    const float* __restrict__ key, const float* __restrict__ val,
    const int* __restrict__ kidx, const int* __restrict__ samp,
    float* __restrict__ ksub, float* __restrict__ vsub, int* __restrict__ sblk) {
  int sidx = blockIdx.x * 4 + (threadIdx.x >> 6);   // 0 .. BH*SAMPLE-1
  int bh = sidx >> 8;                                // SAMPLE_=256
  int d = threadIdx.x & 63;
  int pos = samp[sidx];
  int row = kidx[(size_t)bh * N_ + pos];
  ksub[(size_t)sidx * D_ + d] = key[((size_t)bh * N_ + row) * D_ + d];
  vsub[(size_t)sidx * D_ + d] = val[((size_t)bh * N_ + row) * D_ + d];
  if (d == 0) sblk[sidx] = pos >> 8;                 // BLOCK_=256
}

// ---------------- Kernel 4: MFMA fused attention — dbuf LDS, linear merge -----------
// Double-buffered K/V LDS (72.7 KiB; >=2 WGs/CU == register cap, so free).
// Per chunk: { phase(cur); stage(next -> other buffer); barrier } — stage is
// textually AFTER phase (register-lifetime safety, R7/R12 lesson); staging
// latency overlaps slower waves' phases + the co-resident WG. Barriers 7 -> 4.
// Linear merge (R14): out = (oA + 32*oB)/(lA + 32*lB), single accumulator set.
__global__ __launch_bounds__(512, 4) void attn_kernel(
    const float* __restrict__ query, const float* __restrict__ key,
    const float* __restrict__ value,
    const int* __restrict__ qidx, const int* __restrict__ kidx,
    const float* __restrict__ ksub, const float* __restrict__ vsub,
    const int* __restrict__ sblk, float* __restrict__ out) {
  __shared__ __align__(16) unsigned short KsL[2][CHUNK_ * PADK];   // 36864 B
  __shared__ __align__(16) unsigned short VtL[2][D_ * PADV];       // 33792 B
  __shared__ int sbs[2][CHUNK_];
  __shared__ int qrows[BLOCK_];

  const int bh = blockIdx.x / NBLK_;
  const int blk = blockIdx.x - bh * NBLK_;
  const int tid = threadIdx.x;
  const int w = tid >> 6;       // wave 0..7
  const int lane = tid & 63;
  const int lg = lane >> 4;
  const int lr = lane & 15;
  const float FOLD = 0.18033688011112042f;   // (1/8) * log2(e)

  // ---- staging: thread -> (k-pair kp 0..63, d-octant dq 0..7) ----
  const int kp = tid >> 3, dq = tid & 7;
  auto stage_kv = [&](int buf, const float* kr0, const float* kr1,
                      const float* vr0, const float* vr1) {
    const int kbase = 2 * kp;
    float4 ka0 = *(const float4*)(kr0), ka1 = *(const float4*)(kr0 + 4);
    float4 kb0 = *(const float4*)(kr1), kb1 = *(const float4*)(kr1 + 4);
    u32x4 pk0 = (u32x4){pack2bf(ka0.x, ka0.y), pack2bf(ka0.z, ka0.w),
                        pack2bf(ka1.x, ka1.y), pack2bf(ka1.z, ka1.w)};
    u32x4 pk1 = (u32x4){pack2bf(kb0.x, kb0.y), pack2bf(kb0.z, kb0.w),
                        pack2bf(kb1.x, kb1.y), pack2bf(kb1.z, kb1.w)};
    *(u32x4*)&KsL[buf][(kbase + 0) * PADK + dq * 8] = pk0;
    *(u32x4*)&KsL[buf][(kbase + 1) * PADK + dq * 8] = pk1;
    float4 va0 = *(const float4*)(vr0), va1 = *(const float4*)(vr0 + 4);
    float4 vb0 = *(const float4*)(vr1), vb1 = *(const float4*)(vr1 + 4);
    float a[8] = {va0.x, va0.y, va0.z, va0.w, va1.x, va1.y, va1.z, va1.w};
    float b[8] = {vb0.x, vb0.y, vb0.z, vb0.w, vb1.x, vb1.y, vb1.z, vb1.w};
#pragma unroll
    for (int j = 0; j < 8; j++)
      *(unsigned*)&VtL[buf][(dq * 8 + j) * PADV + kbase] = pack2bf(a[j], b[j]);
  };
  auto stage_block = [&](int c, int buf) {
    size_t ib = (size_t)bh * N_ + blk * BLOCK_ + c * CHUNK_ + 2 * kp;
    int r0 = kidx[ib], r1 = kidx[ib + 1];
    stage_kv(buf, key + ((size_t)bh * N_ + r0) * D_ + dq * 8,
                  key + ((size_t)bh * N_ + r1) * D_ + dq * 8,
                  value + ((size_t)bh * N_ + r0) * D_ + dq * 8,
                  value + ((size_t)bh * N_ + r1) * D_ + dq * 8);
  };
  auto stage_sample = [&](int c, int buf) {
    size_t b0 = ((size_t)bh * SAMPLE_ + c * CHUNK_ + 2 * kp) * D_ + dq * 8;
    stage_kv(buf, ksub + b0, ksub + b0 + D_, vsub + b0, vsub + b0 + D_);
    if (tid < CHUNK_) sbs[buf][tid] = sblk[(size_t)bh * SAMPLE_ + c * CHUNK_ + tid];
  };

  // ---- prologue: chunk 0 -> buf 0, qrows ----
  stage_block(0, 0);
  if (tid < BLOCK_) qrows[tid] = qidx[(size_t)bh * N_ + blk * BLOCK_ + tid];
  __syncthreads();

  // ---- Q fragments (scale folded): lane holds Q[q=qt*16+lr][d=lg*8+h*32..+8] ----
  bf16x8 qf[2][2];
#pragma unroll
  for (int qt = 0; qt < 2; qt++) {
    int qrow = qrows[w * 32 + qt * 16 + lr];
    const float* qp = query + ((size_t)bh * N_ + qrow) * D_ + lg * 8;
#pragma unroll
    for (int h = 0; h < 2; h++) {
      float4 a = *(const float4*)(qp + h * 32);
      float4 b = *(const float4*)(qp + h * 32 + 4);
      union { u32x4 u; bf16x8 v; } cv;
      cv.u = (u32x4){pack2bf(a.x * FOLD, a.y * FOLD), pack2bf(a.z * FOLD, a.w * FOLD),
                     pack2bf(b.x * FOLD, b.y * FOLD), pack2bf(b.z * FOLD, b.w * FOLD)};
      qf[qt][h] = cv.v;
    }
  }

  // ---- SINGLE accumulator set (linear merge) ----
  f32x4 oX[2][4];
  float ls[2] = {0.f, 0.f};
#pragma unroll
  for (int a = 0; a < 2; a++)
#pragma unroll
    for (int b = 0; b < 4; b++) oX[a][b] = (f32x4){0.f, 0.f, 0.f, 0.f};

  auto phase = [&](int buf, bool masked) {
    __builtin_amdgcn_s_setprio(1);
#pragma unroll 2
    for (int kt = 0; kt < 8; kt++) {
      const unsigned short* krow = &KsL[buf][(kt * 16 + lr) * PADK + lg * 8];
      bf16x8 ak0 = *(const bf16x8*)(krow);
      bf16x8 ak1 = *(const bf16x8*)(krow + 32);
      bf16x4 av[4];
#pragma unroll
      for (int dt = 0; dt < 4; dt++)
        av[dt] = *(const bf16x4*)(&VtL[buf][(dt * 16 + lr) * PADV + kt * 16 + lg * 4]);
      float msk[4];
      if (masked) {
#pragma unroll
        for (int r = 0; r < 4; r++)
          msk[r] = (sbs[buf][kt * 16 + lg * 4 + r] == blk) ? 0.f : 32.f;  // 32=N/SAMPLE
      }
      bf16x4 bq[2];
#pragma unroll
      for (int qt = 0; qt < 2; qt++) {
        f32x4 c = (f32x4){0.f, 0.f, 0.f, 0.f};
        c = __builtin_amdgcn_mfma_f32_16x16x32_bf16(ak0, qf[qt][0], c, 0, 0, 0);
        c = __builtin_amdgcn_mfma_f32_16x16x32_bf16(ak1, qf[qt][1], c, 0, 0, 0);
        float w0 = fexp2(c[0]), w1 = fexp2(c[1]);
        float w2 = fexp2(c[2]), w3 = fexp2(c[3]);
        if (masked) { w0 *= msk[0]; w1 *= msk[1]; w2 *= msk[2]; w3 *= msk[3]; }
        ls[qt] += (w0 + w1) + (w2 + w3);
        union { u32x2 u; bf16x4 v; } cv;
        cv.u = (u32x2){pack2bf(w0, w1), pack2bf(w2, w3)};
        bq[qt] = cv.v;
      }
#pragma unroll
      for (int qt = 0; qt < 2; qt++)
#pragma unroll
        for (int dt = 0; dt < 4; dt++)
          oX[qt][dt] = mfma16(av[dt], bq[qt], oX[qt][dt]);
    }
    __builtin_amdgcn_s_setprio(0);
  };

  // ---- chunks: block0(b0), block1(b1), sample0(b0), sample1(b1) ----
  phase(0, false);
  stage_block(1, 1);       // into other buffer; no pre-barrier needed
  __syncthreads();

  phase(1, false);
  stage_sample(0, 0);
  __syncthreads();

  phase(0, true);
  stage_sample(1, 1);
  __syncthreads();

  phase(1, true);

  // ---- normalize + scatter: out = oX / ls ----
#pragma unroll
  for (int qt = 0; qt < 2; qt++) {
    float l = ls[qt];
    l += __shfl_xor(l, 16); l += __shfl_xor(l, 32);
    float winv = 1.f / l;
    int qr = qrows[w * 32 + qt * 16 + lr];
    float* op = out + ((size_t)bh * N_ + qr) * D_ + lg * 4;
#pragma unroll
    for (int dt = 0; dt < 4; dt++) {
      float4 o;
      o.x = winv * oX[qt][dt][0];
      o.y = winv * oX[qt][dt][1];
      o.z = winv * oX[qt][dt][2];
      o.w = winv * oX[qt][dt][3];
      *(float4*)(op + dt * 16) = o;
    }
  }
}

extern "C" void kernel_launch(void* const* d_in, const int* in_sizes, int n_in,
                              void* d_out, int out_size, void* d_ws, size_t ws_size,
                              hipStream_t stream) {
  const float* query = (const float*)d_in[0];
  const float* key   = (const float*)d_in[1];
  const float* value = (const float*)d_in[2];
  const float* pd    = (const float*)d_in[3];
  const int*   samp  = (const int*)d_in[4];
  float* out = (float*)d_out;

  char* w = (char*)d_ws;
  size_t o = 0;
  auto alloc = [&](size_t bytes) { void* p = w + o; o = (o + bytes + 255) & ~(size_t)255; return p; };
  int* qh   = (int*)alloc((size_t)BH_ * N_ * 4);
  int* kh   = (int*)alloc((size_t)BH_ * N_ * 4);
  int* qidx = (int*)alloc((size_t)BH_ * N_ * 4);
  int* kidx = (int*)alloc((size_t)BH_ * N_ * 4);
  float* ksub = (float*)alloc((size_t)BH_ * SAMPLE_ * D_ * 4);
  float* vsub = (float*)alloc((size_t)BH_ * SAMPLE_ * D_ * 4);
  int* sblk = (int*)alloc((size_t)BH_ * SAMPLE_ * 4);

  hash_kernel<<<(2 * BH_ * N_) / 256, 256, 0, stream>>>(query, key, pd, qh, kh);
  sort_kernel<<<2 * BH_, 256, 0, stream>>>(qh, kh, qidx, kidx);
  subgather_kernel<<<BH_ * SAMPLE_ / 4, 256, 0, stream>>>(key, value, kidx, samp, ksub, vsub, sblk);
  attn_kernel<<<BH_ * NBLK_, 512, 0, stream>>>(query, key, value, qidx, kidx,
                                               ksub, vsub, sblk, out);
}

// Round 16
// 113.332 us; speedup vs baseline: 1.1977x; 1.0212x over previous
//
#include <hip/hip_runtime.h>
#include <hip/hip_bf16.h>
#include <math.h>

#define B_ 2
#define H_ 16
#define N_ 8192
#define D_ 64
#define R_ 7
#define BLOCK_ 256
#define SAMPLE_ 256
#define BH_ (B_*H_)
#define NBLK_ (N_/BLOCK_)

#define CHUNK_ 128           // keys staged per chunk
#define PADK 72              // Ks row stride: 144 B
#define PADV 132             // Vt row stride: 264 B

typedef __attribute__((ext_vector_type(8))) short bf16x8;
typedef __attribute__((ext_vector_type(4))) short bf16x4;
typedef __attribute__((ext_vector_type(4))) float f32x4;
typedef __attribute__((ext_vector_type(2))) unsigned int u32x2;
typedef __attribute__((ext_vector_type(4))) unsigned int u32x4;

__device__ inline unsigned short f2bf(float x) {
  __hip_bfloat16 h = __float2bfloat16(x);
  return *(unsigned short*)&h;
}
__device__ inline unsigned int pack2bf(float a, float b) {
  return (unsigned int)f2bf(a) | ((unsigned int)f2bf(b) << 16);
}
__device__ inline float fexp2(float x) {
#if __has_builtin(__builtin_amdgcn_exp2f)
  return __builtin_amdgcn_exp2f(x);
#else
  return exp2f(x);
#endif
}

// PV mfma: D = A(16x16: d x k) * B(16x16: k x q), K=16, bf16
__device__ inline f32x4 mfma16(bf16x4 a, bf16x4 b, f32x4 c) {
#if __has_builtin(__builtin_amdgcn_mfma_f32_16x16x16bf16_1k)
  return __builtin_amdgcn_mfma_f32_16x16x16bf16_1k(a, b, c, 0, 0, 0);
#else
  asm volatile("v_mfma_f32_16x16x16_bf16 %0, %1, %2, %0" : "+v"(c) : "v"(a), "v"(b));
  return c;
#endif
}

// ---------------- Kernel 1: LSH hash (R10 — b128 broadcast spdT) ----------------
__global__ __launch_bounds__(256) void hash_kernel(
    const float* __restrict__ q, const float* __restrict__ k,
    const float* __restrict__ pd, int* __restrict__ qh, int* __restrict__ kh) {
  __shared__ __align__(16) float spdT[R_][D_];   // [r][d]
  for (int i = threadIdx.x; i < D_ * R_; i += blockDim.x) {
    int d = i / R_, r = i - d * R_;              // pd[d*R + r]
    spdT[r][d] = pd[i];
  }
  __syncthreads();
  int tid = blockIdx.x * blockDim.x + threadIdx.x;
  const int half = BH_ * N_;
  const float* src = (tid < half) ? q : k;
  int* dst = (tid < half) ? qh : kh;
  int row = (tid < half) ? tid : tid - half;
  const float4* x4 = (const float4*)(src + (size_t)row * D_);
  float4 x[16];
#pragma unroll
  for (int j = 0; j < 16; j++) x[j] = x4[j];
  int bin = 0;
#pragma unroll
  for (int r = 0; r < R_; r++) {
    float a = 0.f;
#pragma unroll
    for (int j = 0; j < 16; j++) {
      float4 sp = *(const float4*)&spdT[r][4 * j];
      a = fmaf(x[j].x, sp.x, a);
      a = fmaf(x[j].y, sp.y, a);
      a = fmaf(x[j].z, sp.z, a);
      a = fmaf(x[j].w, sp.w, a);
    }
    bin |= (a > 0.f) ? (1 << r) : 0;
  }
  dst[row] = bin ^ (bin >> 1);
}

// ---------------- Kernel 2: stable counting sort, 256 threads/WG (R10) ----------------
__global__ __launch_bounds__(256) void sort_kernel(
    const int* __restrict__ qh, const int* __restrict__ kh,
    int* __restrict__ qidx, int* __restrict__ kidx) {
  int g = blockIdx.x;
  int bh = g & (BH_ - 1);
  bool isK = g >= BH_;
  const int* h = (isK ? kh : qh) + (size_t)bh * N_;
  int* idx = (isK ? kidx : qidx) + (size_t)bh * N_;
  __shared__ unsigned short hist[128][256];   // 64 KiB
  __shared__ int segsum[128][8];
  __shared__ int tot[128];
  __shared__ int off[128];
  const int t = threadIdx.x;

  {  // zero hist (u32x4 = 16 B stores)
    u32x4* hz = (u32x4*)hist;
    for (int i = t; i < 4096; i += 256) hz[i] = (u32x4){0u, 0u, 0u, 0u};
  }
  __syncthreads();

  const int base = t * 32;
  int hv[32];
#pragma unroll
  for (int j = 0; j < 32; j++) hv[j] = h[base + j];
#pragma unroll
  for (int j = 0; j < 32; j++) hist[hv[j]][t]++;
  __syncthreads();

  for (int task = t; task < 1024; task += 256) {
    int b = task >> 3, s = task & 7;
    int sum = 0;
#pragma unroll
    for (int u = 0; u < 32; u++) sum += hist[b][s * 32 + u];
    segsum[b][s] = sum;
  }
  __syncthreads();

  if (t < 128) {
    int run = 0;
#pragma unroll
    for (int s = 0; s < 8; s++) { int x = segsum[t][s]; segsum[t][s] = run; run += x; }
    tot[t] = run;
  }
  __syncthreads();

  if (t == 0) {
    int run = 0;
    for (int b = 0; b < 128; b++) { off[b] = run; run += tot[b]; }
  }
  __syncthreads();

  for (int task = t; task < 1024; task += 256) {
    int b = task >> 3, s = task & 7;
    int run = off[b] + segsum[b][s];
#pragma unroll
    for (int u = 0; u < 32; u++) {
      int x = hist[b][s * 32 + u];
      hist[b][s * 32 + u] = (unsigned short)run;
      run += x;
    }
  }
  __syncthreads();

#pragma unroll
  for (int j = 0; j < 32; j++) {
    int c = hv[j];
    int p = hist[c][t]++;
    idx[p] = base + j;
  }
}

// ---------------- Kernel 3: MFMA fused attention — dbuf, linear merge, direct gather --
// R15 structure + R16: sample chunks gather DIRECTLY (samp -> kidx -> K/V row),
// deleting the subgather kernel and the ksub/vsub round trip. The 3-deep pointer
// chain hides under the dbuf overlap (stage runs after phase, before barrier).
__global__ __launch_bounds__(512, 4) void attn_kernel(
    const float* __restrict__ query, const float* __restrict__ key,
    const float* __restrict__ value,
    const int* __restrict__ qidx, const int* __restrict__ kidx,
    const int* __restrict__ samp, float* __restrict__ out) {
  __shared__ __align__(16) unsigned short KsL[2][CHUNK_ * PADK];   // 36864 B
  __shared__ __align__(16) unsigned short VtL[2][D_ * PADV];       // 33792 B
  __shared__ int sbs[2][CHUNK_];
  __shared__ int qrows[BLOCK_];

  const int bh = blockIdx.x / NBLK_;
  const int blk = blockIdx.x - bh * NBLK_;
  const int tid = threadIdx.x;
  const int w = tid >> 6;       // wave 0..7
  const int lane = tid & 63;
  const int lg = lane >> 4;
  const int lr = lane & 15;
  const float FOLD = 0.18033688011112042f;   // (1/8) * log2(e)

  // ---- staging: thread -> (k-pair kp 0..63, d-octant dq 0..7) ----
  const int kp = tid >> 3, dq = tid & 7;
  auto stage_kv = [&](int buf, int r0, int r1) {
    const float* kr0 = key + ((size_t)bh * N_ + r0) * D_ + dq * 8;
    const float* kr1 = key + ((size_t)bh * N_ + r1) * D_ + dq * 8;
    const float* vr0 = value + ((size_t)bh * N_ + r0) * D_ + dq * 8;
    const float* vr1 = value + ((size_t)bh * N_ + r1) * D_ + dq * 8;
    const int kbase = 2 * kp;
    float4 ka0 = *(const float4*)(kr0), ka1 = *(const float4*)(kr0 + 4);
    float4 kb0 = *(const float4*)(kr1), kb1 = *(const float4*)(kr1 + 4);
    u32x4 pk0 = (u32x4){pack2bf(ka0.x, ka0.y), pack2bf(ka0.z, ka0.w),
                        pack2bf(ka1.x, ka1.y), pack2bf(ka1.z, ka1.w)};
    u32x4 pk1 = (u32x4){pack2bf(kb0.x, kb0.y), pack2bf(kb0.z, kb0.w),
                        pack2bf(kb1.x, kb1.y), pack2bf(kb1.z, kb1.w)};
    *(u32x4*)&KsL[buf][(kbase + 0) * PADK + dq * 8] = pk0;
    *(u32x4*)&KsL[buf][(kbase + 1) * PADK + dq * 8] = pk1;
    float4 va0 = *(const float4*)(vr0), va1 = *(const float4*)(vr0 + 4);
    float4 vb0 = *(const float4*)(vr1), vb1 = *(const float4*)(vr1 + 4);
    float a[8] = {va0.x, va0.y, va0.z, va0.w, va1.x, va1.y, va1.z, va1.w};
    float b[8] = {vb0.x, vb0.y, vb0.z, vb0.w, vb1.x, vb1.y, vb1.z, vb1.w};
#pragma unroll
    for (int j = 0; j < 8; j++)
      *(unsigned*)&VtL[buf][(dq * 8 + j) * PADV + kbase] = pack2bf(a[j], b[j]);
  };
  auto stage_block = [&](int c, int buf) {
    size_t ib = (size_t)bh * N_ + blk * BLOCK_ + c * CHUNK_ + 2 * kp;
    stage_kv(buf, kidx[ib], kidx[ib + 1]);
  };
  auto stage_sample = [&](int c, int buf) {
    size_t sb = (size_t)bh * SAMPLE_ + c * CHUNK_;
    int p0 = samp[sb + 2 * kp], p1 = samp[sb + 2 * kp + 1];
    int r0 = kidx[(size_t)bh * N_ + p0], r1 = kidx[(size_t)bh * N_ + p1];
    stage_kv(buf, r0, r1);
    if (tid < CHUNK_) sbs[buf][tid] = samp[sb + tid] >> 8;   // pos/BLOCK_
  };

  // ---- prologue: chunk 0 -> buf 0, qrows ----
  stage_block(0, 0);
  if (tid < BLOCK_) qrows[tid] = qidx[(size_t)bh * N_ + blk * BLOCK_ + tid];
  __syncthreads();

  // ---- Q fragments (scale folded): lane holds Q[q=qt*16+lr][d=lg*8+h*32..+8] ----
  bf16x8 qf[2][2];
#pragma unroll
  for (int qt = 0; qt < 2; qt++) {
    int qrow = qrows[w * 32 + qt * 16 + lr];
    const float* qp = query + ((size_t)bh * N_ + qrow) * D_ + lg * 8;
#pragma unroll
    for (int h = 0; h < 2; h++) {
      float4 a = *(const float4*)(qp + h * 32);
      float4 b = *(const float4*)(qp + h * 32 + 4);
      union { u32x4 u; bf16x8 v; } cv;
      cv.u = (u32x4){pack2bf(a.x * FOLD, a.y * FOLD), pack2bf(a.z * FOLD, a.w * FOLD),
                     pack2bf(b.x * FOLD, b.y * FOLD), pack2bf(b.z * FOLD, b.w * FOLD)};
      qf[qt][h] = cv.v;
    }
  }

  // ---- SINGLE accumulator set (linear merge, R14) ----
  f32x4 oX[2][4];
  float ls[2] = {0.f, 0.f};
#pragma unroll
  for (int a = 0; a < 2; a++)
#pragma unroll
    for (int b = 0; b < 4; b++) oX[a][b] = (f32x4){0.f, 0.f, 0.f, 0.f};

  auto phase = [&](int buf, bool masked) {
    __builtin_amdgcn_s_setprio(1);
#pragma unroll 2
    for (int kt = 0; kt < 8; kt++) {
      const unsigned short* krow = &KsL[buf][(kt * 16 + lr) * PADK + lg * 8];
      bf16x8 ak0 = *(const bf16x8*)(krow);
      bf16x8 ak1 = *(const bf16x8*)(krow + 32);
      bf16x4 av[4];
#pragma unroll
      for (int dt = 0; dt < 4; dt++)
        av[dt] = *(const bf16x4*)(&VtL[buf][(dt * 16 + lr) * PADV + kt * 16 + lg * 4]);
      float msk[4];
      if (masked) {
#pragma unroll
        for (int r = 0; r < 4; r++)
          msk[r] = (sbs[buf][kt * 16 + lg * 4 + r] == blk) ? 0.f : 32.f;  // 32=N/SAMPLE
      }
      bf16x4 bq[2];
#pragma unroll
      for (int qt = 0; qt < 2; qt++) {
        f32x4 c = (f32x4){0.f, 0.f, 0.f, 0.f};
        c = __builtin_amdgcn_mfma_f32_16x16x32_bf16(ak0, qf[qt][0], c, 0, 0, 0);
        c = __builtin_amdgcn_mfma_f32_16x16x32_bf16(ak1, qf[qt][1], c, 0, 0, 0);
        float w0 = fexp2(c[0]), w1 = fexp2(c[1]);
        float w2 = fexp2(c[2]), w3 = fexp2(c[3]);
        if (masked) { w0 *= msk[0]; w1 *= msk[1]; w2 *= msk[2]; w3 *= msk[3]; }
        ls[qt] += (w0 + w1) + (w2 + w3);
        union { u32x2 u; bf16x4 v; } cv;
        cv.u = (u32x2){pack2bf(w0, w1), pack2bf(w2, w3)};
        bq[qt] = cv.v;
      }
#pragma unroll
      for (int qt = 0; qt < 2; qt++)
#pragma unroll
        for (int dt = 0; dt < 4; dt++)
          oX[qt][dt] = mfma16(av[dt], bq[qt], oX[qt][dt]);
    }
    __builtin_amdgcn_s_setprio(0);
  };

  // ---- chunks: block0(b0), block1(b1), sample0(b0), sample1(b1) ----
  phase(0, false);
  stage_block(1, 1);       // into other buffer; no pre-barrier needed
  __syncthreads();

  phase(1, false);
  stage_sample(0, 0);
  __syncthreads();

  phase(0, true);
  stage_sample(1, 1);
  __syncthreads();

  phase(1, true);

  // ---- normalize + scatter: out = oX / ls ----
#pragma unroll
  for (int qt = 0; qt < 2; qt++) {
    float l = ls[qt];
    l += __shfl_xor(l, 16); l += __shfl_xor(l, 32);
    float winv = 1.f / l;
    int qr = qrows[w * 32 + qt * 16 + lr];
    float* op = out + ((size_t)bh * N_ + qr) * D_ + lg * 4;
#pragma unroll
    for (int dt = 0; dt < 4; dt++) {
      float4 o;
      o.x = winv * oX[qt][dt][0];
      o.y = winv * oX[qt][dt][1];
      o.z = winv * oX[qt][dt][2];
      o.w = winv * oX[qt][dt][3];
      *(float4*)(op + dt * 16) = o;
    }
  }
}

extern "C" void kernel_launch(void* const* d_in, const int* in_sizes, int n_in,
                              void* d_out, int out_size, void* d_ws, size_t ws_size,
                              hipStream_t stream) {
  const float* query = (const float*)d_in[0];
  const float* key   = (const float*)d_in[1];
  const float* value = (const float*)d_in[2];
  const float* pd    = (const float*)d_in[3];
  const int*   samp  = (const int*)d_in[4];
  float* out = (float*)d_out;

  char* w = (char*)d_ws;
  size_t o = 0;
  auto alloc = [&](size_t bytes) { void* p = w + o; o = (o + bytes + 255) & ~(size_t)255; return p; };
  int* qh   = (int*)alloc((size_t)BH_ * N_ * 4);
  int* kh   = (int*)alloc((size_t)BH_ * N_ * 4);
  int* qidx = (int*)alloc((size_t)BH_ * N_ * 4);
  int* kidx = (int*)alloc((size_t)BH_ * N_ * 4);

  hash_kernel<<<(2 * BH_ * N_) / 256, 256, 0, stream>>>(query, key, pd, qh, kh);
  sort_kernel<<<2 * BH_, 256, 0, stream>>>(qh, kh, qidx, kidx);
  attn_kernel<<<BH_ * NBLK_, 512, 0, stream>>>(query, key, value, qidx, kidx,
                                               samp, out);
}

// Round 17
// 112.052 us; speedup vs baseline: 1.2114x; 1.0114x over previous
//
#include <hip/hip_runtime.h>
#include <hip/hip_bf16.h>
#include <math.h>

#define B_ 2
#define H_ 16
#define N_ 8192
#define D_ 64
#define R_ 7
#define BLOCK_ 256
#define SAMPLE_ 256
#define BH_ (B_*H_)
#define NBLK_ (N_/BLOCK_)

#define CHUNK_ 128           // keys staged per chunk
#define PADK 72              // Ks row stride: 144 B
#define PADV 132             // Vt row stride: 264 B

typedef __attribute__((ext_vector_type(8))) short bf16x8;
typedef __attribute__((ext_vector_type(4))) short bf16x4;
typedef __attribute__((ext_vector_type(4))) float f32x4;
typedef __attribute__((ext_vector_type(2))) unsigned int u32x2;
typedef __attribute__((ext_vector_type(4))) unsigned int u32x4;

__device__ inline unsigned short f2bf(float x) {
  __hip_bfloat16 h = __float2bfloat16(x);
  return *(unsigned short*)&h;
}
__device__ inline unsigned int pack2bf(float a, float b) {
  return (unsigned int)f2bf(a) | ((unsigned int)f2bf(b) << 16);
}
__device__ inline float fexp2(float x) {
#if __has_builtin(__builtin_amdgcn_exp2f)
  return __builtin_amdgcn_exp2f(x);
#else
  return exp2f(x);
#endif
}

// PV mfma: D = A(16x16: d x k) * B(16x16: k x q), K=16, bf16
__device__ inline f32x4 mfma16(bf16x4 a, bf16x4 b, f32x4 c) {
#if __has_builtin(__builtin_amdgcn_mfma_f32_16x16x16bf16_1k)
  return __builtin_amdgcn_mfma_f32_16x16x16bf16_1k(a, b, c, 0, 0, 0);
#else
  asm volatile("v_mfma_f32_16x16x16_bf16 %0, %1, %2, %0" : "+v"(c) : "v"(a), "v"(b));
  return c;
#endif
}

// ---------------- Kernel 1: LSH hash (R10 — b128 broadcast spdT) ----------------
__global__ __launch_bounds__(256) void hash_kernel(
    const float* __restrict__ q, const float* __restrict__ k,
    const float* __restrict__ pd, int* __restrict__ qh, int* __restrict__ kh) {
  __shared__ __align__(16) float spdT[R_][D_];   // [r][d]
  for (int i = threadIdx.x; i < D_ * R_; i += blockDim.x) {
    int d = i / R_, r = i - d * R_;              // pd[d*R + r]
    spdT[r][d] = pd[i];
  }
  __syncthreads();
  int tid = blockIdx.x * blockDim.x + threadIdx.x;
  const int half = BH_ * N_;
  const float* src = (tid < half) ? q : k;
  int* dst = (tid < half) ? qh : kh;
  int row = (tid < half) ? tid : tid - half;
  const float4* x4 = (const float4*)(src + (size_t)row * D_);
  float4 x[16];
#pragma unroll
  for (int j = 0; j < 16; j++) x[j] = x4[j];
  int bin = 0;
#pragma unroll
  for (int r = 0; r < R_; r++) {
    float a = 0.f;
#pragma unroll
    for (int j = 0; j < 16; j++) {
      float4 sp = *(const float4*)&spdT[r][4 * j];
      a = fmaf(x[j].x, sp.x, a);
      a = fmaf(x[j].y, sp.y, a);
      a = fmaf(x[j].z, sp.z, a);
      a = fmaf(x[j].w, sp.w, a);
    }
    bin |= (a > 0.f) ? (1 << r) : 0;
  }
  dst[row] = bin ^ (bin >> 1);
}

// ---------------- Kernel 2: stable counting sort, 256 threads/WG (R10) ----------------
__global__ __launch_bounds__(256) void sort_kernel(
    const int* __restrict__ qh, const int* __restrict__ kh,
    int* __restrict__ qidx, int* __restrict__ kidx) {
  int g = blockIdx.x;
  int bh = g & (BH_ - 1);
  bool isK = g >= BH_;
  const int* h = (isK ? kh : qh) + (size_t)bh * N_;
  int* idx = (isK ? kidx : qidx) + (size_t)bh * N_;
  __shared__ unsigned short hist[128][256];   // 64 KiB
  __shared__ int segsum[128][8];
  __shared__ int tot[128];
  __shared__ int off[128];
  const int t = threadIdx.x;

  {  // zero hist (u32x4 = 16 B stores)
    u32x4* hz = (u32x4*)hist;
    for (int i = t; i < 4096; i += 256) hz[i] = (u32x4){0u, 0u, 0u, 0u};
  }
  __syncthreads();

  const int base = t * 32;
  int hv[32];
#pragma unroll
  for (int j = 0; j < 32; j++) hv[j] = h[base + j];
#pragma unroll
  for (int j = 0; j < 32; j++) hist[hv[j]][t]++;
  __syncthreads();

  for (int task = t; task < 1024; task += 256) {
    int b = task >> 3, s = task & 7;
    int sum = 0;
#pragma unroll
    for (int u = 0; u < 32; u++) sum += hist[b][s * 32 + u];
    segsum[b][s] = sum;
  }
  __syncthreads();

  if (t < 128) {
    int run = 0;
#pragma unroll
    for (int s = 0; s < 8; s++) { int x = segsum[t][s]; segsum[t][s] = run; run += x; }
    tot[t] = run;
  }
  __syncthreads();

  if (t == 0) {
    int run = 0;
    for (int b = 0; b < 128; b++) { off[b] = run; run += tot[b]; }
  }
  __syncthreads();

  for (int task = t; task < 1024; task += 256) {
    int b = task >> 3, s = task & 7;
    int run = off[b] + segsum[b][s];
#pragma unroll
    for (int u = 0; u < 32; u++) {
      int x = hist[b][s * 32 + u];
      hist[b][s * 32 + u] = (unsigned short)run;
      run += x;
    }
  }
  __syncthreads();

#pragma unroll
  for (int j = 0; j < 32; j++) {
    int c = hv[j];
    int p = hist[c][t]++;
    idx[p] = base + j;
  }
}

// ---------------- Kernel 3: MFMA fused attention ----------------
// R16 base (dbuf LDS, linear merge, direct sample gather) + R17:
//  (a) ls on the MFMA pipe via ones-fragment accumulator (+8 AGPR, -7 VALU/kt)
//  (b) kt loop unroll 4 (ILP + LDS offset-immediate folding)
__global__ __launch_bounds__(512, 4) void attn_kernel(
    const float* __restrict__ query, const float* __restrict__ key,
    const float* __restrict__ value,
    const int* __restrict__ qidx, const int* __restrict__ kidx,
    const int* __restrict__ samp, float* __restrict__ out) {
  __shared__ __align__(16) unsigned short KsL[2][CHUNK_ * PADK];   // 36864 B
  __shared__ __align__(16) unsigned short VtL[2][D_ * PADV];       // 33792 B
  __shared__ int sbs[2][CHUNK_];
  __shared__ int qrows[BLOCK_];

  const int bh = blockIdx.x / NBLK_;
  const int blk = blockIdx.x - bh * NBLK_;
  const int tid = threadIdx.x;
  const int w = tid >> 6;       // wave 0..7
  const int lane = tid & 63;
  const int lg = lane >> 4;
  const int lr = lane & 15;
  const float FOLD = 0.18033688011112042f;   // (1/8) * log2(e)

  // ---- staging: thread -> (k-pair kp 0..63, d-octant dq 0..7) ----
  const int kp = tid >> 3, dq = tid & 7;
  auto stage_kv = [&](int buf, int r0, int r1) {
    const float* kr0 = key + ((size_t)bh * N_ + r0) * D_ + dq * 8;
    const float* kr1 = key + ((size_t)bh * N_ + r1) * D_ + dq * 8;
    const float* vr0 = value + ((size_t)bh * N_ + r0) * D_ + dq * 8;
    const float* vr1 = value + ((size_t)bh * N_ + r1) * D_ + dq * 8;
    const int kbase = 2 * kp;
    float4 ka0 = *(const float4*)(kr0), ka1 = *(const float4*)(kr0 + 4);
    float4 kb0 = *(const float4*)(kr1), kb1 = *(const float4*)(kr1 + 4);
    u32x4 pk0 = (u32x4){pack2bf(ka0.x, ka0.y), pack2bf(ka0.z, ka0.w),
                        pack2bf(ka1.x, ka1.y), pack2bf(ka1.z, ka1.w)};
    u32x4 pk1 = (u32x4){pack2bf(kb0.x, kb0.y), pack2bf(kb0.z, kb0.w),
                        pack2bf(kb1.x, kb1.y), pack2bf(kb1.z, kb1.w)};
    *(u32x4*)&KsL[buf][(kbase + 0) * PADK + dq * 8] = pk0;
    *(u32x4*)&KsL[buf][(kbase + 1) * PADK + dq * 8] = pk1;
    float4 va0 = *(const float4*)(vr0), va1 = *(const float4*)(vr0 + 4);
    float4 vb0 = *(const float4*)(vr1), vb1 = *(const float4*)(vr1 + 4);
    float a[8] = {va0.x, va0.y, va0.z, va0.w, va1.x, va1.y, va1.z, va1.w};
    float b[8] = {vb0.x, vb0.y, vb0.z, vb0.w, vb1.x, vb1.y, vb1.z, vb1.w};
#pragma unroll
    for (int j = 0; j < 8; j++)
      *(unsigned*)&VtL[buf][(dq * 8 + j) * PADV + kbase] = pack2bf(a[j], b[j]);
  };
  auto stage_block = [&](int c, int buf) {
    size_t ib = (size_t)bh * N_ + blk * BLOCK_ + c * CHUNK_ + 2 * kp;
    stage_kv(buf, kidx[ib], kidx[ib + 1]);
  };
  auto stage_sample = [&](int c, int buf) {
    size_t sb = (size_t)bh * SAMPLE_ + c * CHUNK_;
    int p0 = samp[sb + 2 * kp], p1 = samp[sb + 2 * kp + 1];
    int r0 = kidx[(size_t)bh * N_ + p0], r1 = kidx[(size_t)bh * N_ + p1];
    stage_kv(buf, r0, r1);
    if (tid < CHUNK_) sbs[buf][tid] = samp[sb + tid] >> 8;   // pos/BLOCK_
  };

  // ---- prologue: chunk 0 -> buf 0, qrows ----
  stage_block(0, 0);
  if (tid < BLOCK_) qrows[tid] = qidx[(size_t)bh * N_ + blk * BLOCK_ + tid];
  __syncthreads();

  // ---- Q fragments (scale folded): lane holds Q[q=qt*16+lr][d=lg*8+h*32..+8] ----
  bf16x8 qf[2][2];
#pragma unroll
  for (int qt = 0; qt < 2; qt++) {
    int qrow = qrows[w * 32 + qt * 16 + lr];
    const float* qp = query + ((size_t)bh * N_ + qrow) * D_ + lg * 8;
#pragma unroll
    for (int h = 0; h < 2; h++) {
      float4 a = *(const float4*)(qp + h * 32);
      float4 b = *(const float4*)(qp + h * 32 + 4);
      union { u32x4 u; bf16x8 v; } cv;
      cv.u = (u32x4){pack2bf(a.x * FOLD, a.y * FOLD), pack2bf(a.z * FOLD, a.w * FOLD),
                     pack2bf(b.x * FOLD, b.y * FOLD), pack2bf(b.z * FOLD, b.w * FOLD)};
      qf[qt][h] = cv.v;
    }
  }

  // ---- ones A-fragment: A[row 0][*]=1 -> D row 0 = column sums of W (the ls) ----
  const bf16x4 avONE = (lr == 0)
      ? (bf16x4){(short)0x3F80, (short)0x3F80, (short)0x3F80, (short)0x3F80}
      : (bf16x4){0, 0, 0, 0};

  // ---- SINGLE accumulator set (linear merge) + ls accumulators on MFMA pipe ----
  f32x4 oX[2][4], oLS[2];
#pragma unroll
  for (int a = 0; a < 2; a++) {
    oLS[a] = (f32x4){0.f, 0.f, 0.f, 0.f};
#pragma unroll
    for (int b = 0; b < 4; b++) oX[a][b] = (f32x4){0.f, 0.f, 0.f, 0.f};
  }

  auto phase = [&](int buf, bool masked) {
    __builtin_amdgcn_s_setprio(1);
#pragma unroll 4
    for (int kt = 0; kt < 8; kt++) {
      const unsigned short* krow = &KsL[buf][(kt * 16 + lr) * PADK + lg * 8];
      bf16x8 ak0 = *(const bf16x8*)(krow);
      bf16x8 ak1 = *(const bf16x8*)(krow + 32);
      bf16x4 av[4];
#pragma unroll
      for (int dt = 0; dt < 4; dt++)
        av[dt] = *(const bf16x4*)(&VtL[buf][(dt * 16 + lr) * PADV + kt * 16 + lg * 4]);
      float msk[4];
      if (masked) {
#pragma unroll
        for (int r = 0; r < 4; r++)
          msk[r] = (sbs[buf][kt * 16 + lg * 4 + r] == blk) ? 0.f : 32.f;  // 32=N/SAMPLE
      }
      bf16x4 bq[2];
#pragma unroll
      for (int qt = 0; qt < 2; qt++) {
        f32x4 c = (f32x4){0.f, 0.f, 0.f, 0.f};
        c = __builtin_amdgcn_mfma_f32_16x16x32_bf16(ak0, qf[qt][0], c, 0, 0, 0);
        c = __builtin_amdgcn_mfma_f32_16x16x32_bf16(ak1, qf[qt][1], c, 0, 0, 0);
        float w0 = fexp2(c[0]), w1 = fexp2(c[1]);
        float w2 = fexp2(c[2]), w3 = fexp2(c[3]);
        if (masked) { w0 *= msk[0]; w1 *= msk[1]; w2 *= msk[2]; w3 *= msk[3]; }
        union { u32x2 u; bf16x4 v; } cv;
        cv.u = (u32x2){pack2bf(w0, w1), pack2bf(w2, w3)};
        bq[qt] = cv.v;
      }
#pragma unroll
      for (int qt = 0; qt < 2; qt++) {
#pragma unroll
        for (int dt = 0; dt < 4; dt++)
          oX[qt][dt] = mfma16(av[dt], bq[qt], oX[qt][dt]);
        oLS[qt] = mfma16(avONE, bq[qt], oLS[qt]);   // ls on the MFMA pipe
      }
    }
    __builtin_amdgcn_s_setprio(0);
  };

  // ---- chunks: block0(b0), block1(b1), sample0(b0), sample1(b1) ----
  phase(0, false);
  stage_block(1, 1);       // into other buffer; no pre-barrier needed
  __syncthreads();

  phase(1, false);
  stage_sample(0, 0);
  __syncthreads();

  phase(0, true);
  stage_sample(1, 1);
  __syncthreads();

  phase(1, true);

  // ---- normalize + scatter: out = oX / ls ----
#pragma unroll
  for (int qt = 0; qt < 2; qt++) {
    float l = __shfl(oLS[qt][0], lr);   // lane (lg=0, lr) holds sum for q=lr
    float winv = 1.f / l;
    int qr = qrows[w * 32 + qt * 16 + lr];
    float* op = out + ((size_t)bh * N_ + qr) * D_ + lg * 4;
#pragma unroll
    for (int dt = 0; dt < 4; dt++) {
      float4 o;
      o.x = winv * oX[qt][dt][0];
      o.y = winv * oX[qt][dt][1];
      o.z = winv * oX[qt][dt][2];
      o.w = winv * oX[qt][dt][3];
      *(float4*)(op + dt * 16) = o;
    }
  }
}

extern "C" void kernel_launch(void* const* d_in, const int* in_sizes, int n_in,
                              void* d_out, int out_size, void* d_ws, size_t ws_size,
                              hipStream_t stream) {
  const float* query = (const float*)d_in[0];
  const float* key   = (const float*)d_in[1];
  const float* value = (const float*)d_in[2];
  const float* pd    = (const float*)d_in[3];
  const int*   samp  = (const int*)d_in[4];
  float* out = (float*)d_out;

  char* w = (char*)d_ws;
  size_t o = 0;
  auto alloc = [&](size_t bytes) { void* p = w + o; o = (o + bytes + 255) & ~(size_t)255; return p; };
  int* qh   = (int*)alloc((size_t)BH_ * N_ * 4);
  int* kh   = (int*)alloc((size_t)BH_ * N_ * 4);
  int* qidx = (int*)alloc((size_t)BH_ * N_ * 4);
  int* kidx = (int*)alloc((size_t)BH_ * N_ * 4);

  hash_kernel<<<(2 * BH_ * N_) / 256, 256, 0, stream>>>(query, key, pd, qh, kh);
  sort_kernel<<<2 * BH_, 256, 0, stream>>>(qh, kh, qidx, kidx);
  attn_kernel<<<BH_ * NBLK_, 512, 0, stream>>>(query, key, value, qidx, kidx,
                                               samp, out);
}

// Round 18
// 108.684 us; speedup vs baseline: 1.2489x; 1.0310x over previous
//
#include <hip/hip_runtime.h>
#include <hip/hip_bf16.h>
#include <math.h>

#define B_ 2
#define H_ 16
#define N_ 8192
#define D_ 64
#define R_ 7
#define BLOCK_ 256
#define SAMPLE_ 256
#define BH_ (B_*H_)
#define NBLK_ (N_/BLOCK_)

#define CHUNK_ 128           // keys staged per chunk
#define PADK 72              // Ks row stride: 144 B
#define PADV 132             // Vt row stride: 264 B

typedef __attribute__((ext_vector_type(8))) short bf16x8;
typedef __attribute__((ext_vector_type(4))) short bf16x4;
typedef __attribute__((ext_vector_type(4))) float f32x4;
typedef __attribute__((ext_vector_type(2))) unsigned int u32x2;
typedef __attribute__((ext_vector_type(4))) unsigned int u32x4;

__device__ inline unsigned short f2bf(float x) {
  __hip_bfloat16 h = __float2bfloat16(x);
  return *(unsigned short*)&h;
}
__device__ inline unsigned int pack2bf(float a, float b) {
  return (unsigned int)f2bf(a) | ((unsigned int)f2bf(b) << 16);
}
__device__ inline float fexp2(float x) {
#if __has_builtin(__builtin_amdgcn_exp2f)
  return __builtin_amdgcn_exp2f(x);
#else
  return exp2f(x);
#endif
}

// ---------------- Kernel 1: LSH hash (R10 — b128 broadcast spdT) ----------------
__global__ __launch_bounds__(256) void hash_kernel(
    const float* __restrict__ q, const float* __restrict__ k,
    const float* __restrict__ pd, int* __restrict__ qh, int* __restrict__ kh) {
  __shared__ __align__(16) float spdT[R_][D_];   // [r][d]
  for (int i = threadIdx.x; i < D_ * R_; i += blockDim.x) {
    int d = i / R_, r = i - d * R_;              // pd[d*R + r]
    spdT[r][d] = pd[i];
  }
  __syncthreads();
  int tid = blockIdx.x * blockDim.x + threadIdx.x;
  const int half = BH_ * N_;
  const float* src = (tid < half) ? q : k;
  int* dst = (tid < half) ? qh : kh;
  int row = (tid < half) ? tid : tid - half;
  const float4* x4 = (const float4*)(src + (size_t)row * D_);
  float4 x[16];
#pragma unroll
  for (int j = 0; j < 16; j++) x[j] = x4[j];
  int bin = 0;
#pragma unroll
  for (int r = 0; r < R_; r++) {
    float a = 0.f;
#pragma unroll
    for (int j = 0; j < 16; j++) {
      float4 sp = *(const float4*)&spdT[r][4 * j];
      a = fmaf(x[j].x, sp.x, a);
      a = fmaf(x[j].y, sp.y, a);
      a = fmaf(x[j].z, sp.z, a);
      a = fmaf(x[j].w, sp.w, a);
    }
    bin |= (a > 0.f) ? (1 << r) : 0;
  }
  dst[row] = bin ^ (bin >> 1);
}

// ---------------- Kernel 2: stable counting sort, 256 threads/WG (R10) ----------------
__global__ __launch_bounds__(256) void sort_kernel(
    const int* __restrict__ qh, const int* __restrict__ kh,
    int* __restrict__ qidx, int* __restrict__ kidx) {
  int g = blockIdx.x;
  int bh = g & (BH_ - 1);
  bool isK = g >= BH_;
  const int* h = (isK ? kh : qh) + (size_t)bh * N_;
  int* idx = (isK ? kidx : qidx) + (size_t)bh * N_;
  __shared__ unsigned short hist[128][256];   // 64 KiB
  __shared__ int segsum[128][8];
  __shared__ int tot[128];
  __shared__ int off[128];
  const int t = threadIdx.x;

  {  // zero hist (u32x4 = 16 B stores)
    u32x4* hz = (u32x4*)hist;
    for (int i = t; i < 4096; i += 256) hz[i] = (u32x4){0u, 0u, 0u, 0u};
  }
  __syncthreads();

  const int base = t * 32;
  int hv[32];
#pragma unroll
  for (int j = 0; j < 32; j++) hv[j] = h[base + j];
#pragma unroll
  for (int j = 0; j < 32; j++) hist[hv[j]][t]++;
  __syncthreads();

  for (int task = t; task < 1024; task += 256) {
    int b = task >> 3, s = task & 7;
    int sum = 0;
#pragma unroll
    for (int u = 0; u < 32; u++) sum += hist[b][s * 32 + u];
    segsum[b][s] = sum;
  }
  __syncthreads();

  if (t < 128) {
    int run = 0;
#pragma unroll
    for (int s = 0; s < 8; s++) { int x = segsum[t][s]; segsum[t][s] = run; run += x; }
    tot[t] = run;
  }
  __syncthreads();

  if (t == 0) {
    int run = 0;
    for (int b = 0; b < 128; b++) { off[b] = run; run += tot[b]; }
  }
  __syncthreads();

  for (int task = t; task < 1024; task += 256) {
    int b = task >> 3, s = task & 7;
    int run = off[b] + segsum[b][s];
#pragma unroll
    for (int u = 0; u < 32; u++) {
      int x = hist[b][s * 32 + u];
      hist[b][s * 32 + u] = (unsigned short)run;
      run += x;
    }
  }
  __syncthreads();

#pragma unroll
  for (int j = 0; j < 32; j++) {
    int c = hv[j];
    int p = hist[c][t]++;
    idx[p] = base + j;
  }
}

// ---------------- Kernel 3: MFMA fused attention ----------------
// R17 base + R18: PV upgraded to mfma_f32_16x16x32 over kt-PAIRS via a
// thread-local key permutation: B-frag slots lg*8..+3 <- tile-a scores
// (QK C-layout already lane-local), +4..+7 <- tile-b; A-frag = two b64 V^T
// reads concatenated with the SAME permutation. Zero cross-lane traffic;
// PV+ls MFMA issues per phase: 96 -> 48 (each 2x FLOP).
__global__ __launch_bounds__(512, 4) void attn_kernel(
    const float* __restrict__ query, const float* __restrict__ key,
    const float* __restrict__ value,
    const int* __restrict__ qidx, const int* __restrict__ kidx,
    const int* __restrict__ samp, float* __restrict__ out) {
  __shared__ __align__(16) unsigned short KsL[2][CHUNK_ * PADK];   // 36864 B
  __shared__ __align__(16) unsigned short VtL[2][D_ * PADV];       // 33792 B
  __shared__ int sbs[2][CHUNK_];
  __shared__ int qrows[BLOCK_];

  const int bh = blockIdx.x / NBLK_;
  const int blk = blockIdx.x - bh * NBLK_;
  const int tid = threadIdx.x;
  const int w = tid >> 6;       // wave 0..7
  const int lane = tid & 63;
  const int lg = lane >> 4;
  const int lr = lane & 15;
  const float FOLD = 0.18033688011112042f;   // (1/8) * log2(e)

  // ---- staging: thread -> (k-pair kp 0..63, d-octant dq 0..7) ----
  const int kp = tid >> 3, dq = tid & 7;
  auto stage_kv = [&](int buf, int r0, int r1) {
    const float* kr0 = key + ((size_t)bh * N_ + r0) * D_ + dq * 8;
    const float* kr1 = key + ((size_t)bh * N_ + r1) * D_ + dq * 8;
    const float* vr0 = value + ((size_t)bh * N_ + r0) * D_ + dq * 8;
    const float* vr1 = value + ((size_t)bh * N_ + r1) * D_ + dq * 8;
    const int kbase = 2 * kp;
    float4 ka0 = *(const float4*)(kr0), ka1 = *(const float4*)(kr0 + 4);
    float4 kb0 = *(const float4*)(kr1), kb1 = *(const float4*)(kr1 + 4);
    u32x4 pk0 = (u32x4){pack2bf(ka0.x, ka0.y), pack2bf(ka0.z, ka0.w),
                        pack2bf(ka1.x, ka1.y), pack2bf(ka1.z, ka1.w)};
    u32x4 pk1 = (u32x4){pack2bf(kb0.x, kb0.y), pack2bf(kb0.z, kb0.w),
                        pack2bf(kb1.x, kb1.y), pack2bf(kb1.z, kb1.w)};
    *(u32x4*)&KsL[buf][(kbase + 0) * PADK + dq * 8] = pk0;
    *(u32x4*)&KsL[buf][(kbase + 1) * PADK + dq * 8] = pk1;
    float4 va0 = *(const float4*)(vr0), va1 = *(const float4*)(vr0 + 4);
    float4 vb0 = *(const float4*)(vr1), vb1 = *(const float4*)(vr1 + 4);
    float a[8] = {va0.x, va0.y, va0.z, va0.w, va1.x, va1.y, va1.z, va1.w};
    float b[8] = {vb0.x, vb0.y, vb0.z, vb0.w, vb1.x, vb1.y, vb1.z, vb1.w};
#pragma unroll
    for (int j = 0; j < 8; j++)
      *(unsigned*)&VtL[buf][(dq * 8 + j) * PADV + kbase] = pack2bf(a[j], b[j]);
  };
  auto stage_block = [&](int c, int buf) {
    size_t ib = (size_t)bh * N_ + blk * BLOCK_ + c * CHUNK_ + 2 * kp;
    stage_kv(buf, kidx[ib], kidx[ib + 1]);
  };
  auto stage_sample = [&](int c, int buf) {
    size_t sb = (size_t)bh * SAMPLE_ + c * CHUNK_;
    int p0 = samp[sb + 2 * kp], p1 = samp[sb + 2 * kp + 1];
    int r0 = kidx[(size_t)bh * N_ + p0], r1 = kidx[(size_t)bh * N_ + p1];
    stage_kv(buf, r0, r1);
    if (tid < CHUNK_) sbs[buf][tid] = samp[sb + tid] >> 8;   // pos/BLOCK_
  };

  // ---- prologue: chunk 0 -> buf 0, qrows ----
  stage_block(0, 0);
  if (tid < BLOCK_) qrows[tid] = qidx[(size_t)bh * N_ + blk * BLOCK_ + tid];
  __syncthreads();

  // ---- Q fragments (scale folded): lane holds Q[q=qt*16+lr][d=lg*8+h*32..+8] ----
  bf16x8 qf[2][2];
#pragma unroll
  for (int qt = 0; qt < 2; qt++) {
    int qrow = qrows[w * 32 + qt * 16 + lr];
    const float* qp = query + ((size_t)bh * N_ + qrow) * D_ + lg * 8;
#pragma unroll
    for (int h = 0; h < 2; h++) {
      float4 a = *(const float4*)(qp + h * 32);
      float4 b = *(const float4*)(qp + h * 32 + 4);
      union { u32x4 u; bf16x8 v; } cv;
      cv.u = (u32x4){pack2bf(a.x * FOLD, a.y * FOLD), pack2bf(a.z * FOLD, a.w * FOLD),
                     pack2bf(b.x * FOLD, b.y * FOLD), pack2bf(b.z * FOLD, b.w * FOLD)};
      qf[qt][h] = cv.v;
    }
  }

  // ---- ones A-fragment (8-wide): A[row 0][*]=1 -> D row 0 = col sums of W ----
  const bf16x8 avONE8 = (lr == 0)
      ? (bf16x8){(short)0x3F80, (short)0x3F80, (short)0x3F80, (short)0x3F80,
                 (short)0x3F80, (short)0x3F80, (short)0x3F80, (short)0x3F80}
      : (bf16x8){0, 0, 0, 0, 0, 0, 0, 0};

  // ---- SINGLE accumulator set (linear merge) + ls accumulators on MFMA pipe ----
  f32x4 oX[2][4], oLS[2];
#pragma unroll
  for (int a = 0; a < 2; a++) {
    oLS[a] = (f32x4){0.f, 0.f, 0.f, 0.f};
#pragma unroll
    for (int b = 0; b < 4; b++) oX[a][b] = (f32x4){0.f, 0.f, 0.f, 0.f};
  }

  auto phase = [&](int buf, bool masked) {
    __builtin_amdgcn_s_setprio(1);
#pragma unroll 2
    for (int ktp = 0; ktp < 4; ktp++) {
      const int kta = 2 * ktp, ktb = 2 * ktp + 1;
      const unsigned short* krow0 = &KsL[buf][(kta * 16 + lr) * PADK + lg * 8];
      const unsigned short* krow1 = &KsL[buf][(ktb * 16 + lr) * PADK + lg * 8];
      bf16x8 a0k0 = *(const bf16x8*)(krow0);
      bf16x8 a0k1 = *(const bf16x8*)(krow0 + 32);
      bf16x8 a1k0 = *(const bf16x8*)(krow1);
      bf16x8 a1k1 = *(const bf16x8*)(krow1 + 32);
      // V^T fragments under the pair-permutation: {tile-a 4 keys, tile-b 4 keys}
      bf16x8 av[4];
#pragma unroll
      for (int dt = 0; dt < 4; dt++) {
        const unsigned short* vrow = &VtL[buf][(dt * 16 + lr) * PADV];
        u32x2 lo = *(const u32x2*)(vrow + kta * 16 + lg * 4);
        u32x2 hi = *(const u32x2*)(vrow + ktb * 16 + lg * 4);
        union { u32x4 u; bf16x8 v; } cv;
        cv.u = (u32x4){lo[0], lo[1], hi[0], hi[1]};
        av[dt] = cv.v;
      }
      float mska[4], mskb[4];
      if (masked) {
#pragma unroll
        for (int r = 0; r < 4; r++) {
          mska[r] = (sbs[buf][kta * 16 + lg * 4 + r] == blk) ? 0.f : 32.f;
          mskb[r] = (sbs[buf][ktb * 16 + lg * 4 + r] == blk) ? 0.f : 32.f;
        }
      }
      bf16x8 bq[2];
#pragma unroll
      for (int qt = 0; qt < 2; qt++) {
        f32x4 ca = (f32x4){0.f, 0.f, 0.f, 0.f};
        ca = __builtin_amdgcn_mfma_f32_16x16x32_bf16(a0k0, qf[qt][0], ca, 0, 0, 0);
        ca = __builtin_amdgcn_mfma_f32_16x16x32_bf16(a0k1, qf[qt][1], ca, 0, 0, 0);
        f32x4 cb = (f32x4){0.f, 0.f, 0.f, 0.f};
        cb = __builtin_amdgcn_mfma_f32_16x16x32_bf16(a1k0, qf[qt][0], cb, 0, 0, 0);
        cb = __builtin_amdgcn_mfma_f32_16x16x32_bf16(a1k1, qf[qt][1], cb, 0, 0, 0);
        float wa0 = fexp2(ca[0]), wa1 = fexp2(ca[1]), wa2 = fexp2(ca[2]), wa3 = fexp2(ca[3]);
        float wb0 = fexp2(cb[0]), wb1 = fexp2(cb[1]), wb2 = fexp2(cb[2]), wb3 = fexp2(cb[3]);
        if (masked) {
          wa0 *= mska[0]; wa1 *= mska[1]; wa2 *= mska[2]; wa3 *= mska[3];
          wb0 *= mskb[0]; wb1 *= mskb[1]; wb2 *= mskb[2]; wb3 *= mskb[3];
        }
        union { u32x4 u; bf16x8 v; } cv;
        cv.u = (u32x4){pack2bf(wa0, wa1), pack2bf(wa2, wa3),
                       pack2bf(wb0, wb1), pack2bf(wb2, wb3)};
        bq[qt] = cv.v;
      }
#pragma unroll
      for (int qt = 0; qt < 2; qt++) {
#pragma unroll
        for (int dt = 0; dt < 4; dt++)
          oX[qt][dt] = __builtin_amdgcn_mfma_f32_16x16x32_bf16(av[dt], bq[qt], oX[qt][dt], 0, 0, 0);
        oLS[qt] = __builtin_amdgcn_mfma_f32_16x16x32_bf16(avONE8, bq[qt], oLS[qt], 0, 0, 0);
      }
    }
    __builtin_amdgcn_s_setprio(0);
  };

  // ---- chunks: block0(b0), block1(b1), sample0(b0), sample1(b1) ----
  phase(0, false);
  stage_block(1, 1);       // into other buffer; no pre-barrier needed
  __syncthreads();

  phase(1, false);
  stage_sample(0, 0);
  __syncthreads();

  phase(0, true);
  stage_sample(1, 1);
  __syncthreads();

  phase(1, true);

  // ---- normalize + scatter: out = oX / ls ----
#pragma unroll
  for (int qt = 0; qt < 2; qt++) {
    float l = __shfl(oLS[qt][0], lr);   // lane (lg=0, lr) holds sum for q=lr
    float winv = 1.f / l;
    int qr = qrows[w * 32 + qt * 16 + lr];
    float* op = out + ((size_t)bh * N_ + qr) * D_ + lg * 4;
#pragma unroll
    for (int dt = 0; dt < 4; dt++) {
      float4 o;
      o.x = winv * oX[qt][dt][0];
      o.y = winv * oX[qt][dt][1];
      o.z = winv * oX[qt][dt][2];
      o.w = winv * oX[qt][dt][3];
      *(float4*)(op + dt * 16) = o;
    }
  }
}

extern "C" void kernel_launch(void* const* d_in, const int* in_sizes, int n_in,
                              void* d_out, int out_size, void* d_ws, size_t ws_size,
                              hipStream_t stream) {
  const float* query = (const float*)d_in[0];
  const float* key   = (const float*)d_in[1];
  const float* value = (const float*)d_in[2];
  const float* pd    = (const float*)d_in[3];
  const int*   samp  = (const int*)d_in[4];
  float* out = (float*)d_out;

  char* w = (char*)d_ws;
  size_t o = 0;
  auto alloc = [&](size_t bytes) { void* p = w + o; o = (o + bytes + 255) & ~(size_t)255; return p; };
  int* qh   = (int*)alloc((size_t)BH_ * N_ * 4);
  int* kh   = (int*)alloc((size_t)BH_ * N_ * 4);
  int* qidx = (int*)alloc((size_t)BH_ * N_ * 4);
  int* kidx = (int*)alloc((size_t)BH_ * N_ * 4);

  hash_kernel<<<(2 * BH_ * N_) / 256, 256, 0, stream>>>(query, key, pd, qh, kh);
  sort_kernel<<<2 * BH_, 256, 0, stream>>>(qh, kh, qidx, kidx);
  attn_kernel<<<BH_ * NBLK_, 512, 0, stream>>>(query, key, value, qidx, kidx,
                                               samp, out);
}